// Round 7
// baseline (382.435 us; speedup 1.0000x reference)
//
#include <hip/hip_runtime.h>
#include <math.h>

#define NPTS 524288
#define LOG2T 19
#define TSIZE (1u << LOG2T)
#define TMASK (TSIZE - 1u)

typedef unsigned int uint32;
typedef unsigned short ushort16;

typedef __attribute__((ext_vector_type(8))) short short8;
typedef __attribute__((ext_vector_type(4))) float f32x4;

__device__ __forceinline__ float bf2f(ushort16 u) {
    union { uint32 i; float f; } v; v.i = ((uint32)u) << 16; return v.f;
}
__device__ __forceinline__ ushort16 f2bf(float f) {
    union { float f; uint32 i; } v; v.f = f;
    uint32 r = v.i + 0x7fffu + ((v.i >> 16) & 1u);   // RNE
    return (ushort16)(r >> 16);
}
__device__ __forceinline__ uint32 pack2(float a, float b) {
    return (uint32)f2bf(a) | ((uint32)f2bf(b) << 16);
}
// dtype-flexible scalar load: fp32 or bf16 per runtime flag (block-uniform)
__device__ __forceinline__ float ldin(const void* p, int i, bool f32) {
    return f32 ? ((const float*)p)[i] : bf2f(((const ushort16*)p)[i]);
}

struct Scal16 { float s[16]; };
struct Freq4  { float f[4]; };

// ---------------------------------------------------------------------------
// Kernel A (unchanged from R6, 207 us measured): level-major hash encode,
// single launch, 2 phases x 8 levels; lvl = phase*8 + (blockIdx&7) pins each
// level's 4 MiB fp32 sub-table to one XCD's L2. x-corner pairing: when
// idx_ce == idx_fl^1 (~50%), one aligned 16B load serves both corners
// (~6 L2 requests per (pt,lvl) instead of 8).
// enc[lvl*NPTS+pt] = packed bf16 (feat0 | feat1<<16)
// ---------------------------------------------------------------------------
__global__ __launch_bounds__(256) void k_hash(const void* __restrict__ pos,
                                              const void* __restrict__ tbl,
                                              uint32* __restrict__ enc,
                                              Scal16 sc) {
    __shared__ int sFlag;
    int tid = threadIdx.x;
    if (tid < 64) {   // dtype detect: positions in [0,1); bf16-misread of fp32 -> garbage
        const ushort16* ph = (const ushort16*)pos;
        float v0 = bf2f(ph[tid]), v1 = bf2f(ph[tid + 64]);
        bool odd = !(fabsf(v0) <= 4.f) || !(fabsf(v1) <= 4.f);
        unsigned long long m = __ballot(odd);
        if (tid == 0) sFlag = (m != 0ull) ? 1 : 0;
    }
    __syncthreads();
    const bool f32 = (sFlag != 0);

    int lvl = ((blockIdx.x >> 14) << 3) + (blockIdx.x & 7);
    int pt = ((blockIdx.x >> 3) & 2047) * 256 + tid;

    float s = sc.s[lvl];
    float x = ldin(pos, 3 * pt, f32), y = ldin(pos, 3 * pt + 1, f32), z = ldin(pos, 3 * pt + 2, f32);
    float sx = x * s, sy = y * s, sz = z * s;
    float fx = floorf(sx), fy = floorf(sy), fz = floorf(sz);
    float cx = ceilf(sx), cy = ceilf(sy), cz = ceilf(sz);   // ceil, NOT floor+1 (matches ref)
    float ox = sx - fx, oy = sy - fy, oz = sz - fz;
    uint32 hx0 = (uint32)(int)fx;                       // prime[0] = 1
    uint32 hx1 = (uint32)(int)cx;
    uint32 hy0 = (uint32)(int)fy * 2654435761u;
    uint32 hy1 = (uint32)(int)cy * 2654435761u;
    uint32 hz0 = (uint32)(int)fz * 805459861u;
    uint32 hz1 = (uint32)(int)cz * 805459861u;
    uint32 base = (uint32)lvl << LOG2T;
    float wx0 = 1.f - ox, wy0 = 1.f - oy, wz0 = 1.f - oz;

    float a0 = 0.f, a1 = 0.f;
    if (f32) {
        const float* tf = (const float*)tbl;
#pragma unroll
        for (int yz = 0; yz < 4; ++yz) {
            uint32 m = ((yz & 1) ? hy1 : hy0) ^ ((yz & 2) ? hz1 : hz0);
            float wyz = ((yz & 1) ? oy : wy0) * ((yz & 2) ? oz : wz0);
            uint32 i0 = ((hx0 ^ m) & TMASK) + base;
            uint32 i1 = ((hx1 ^ m) & TMASK) + base;
            float4 pv = *(const float4*)(tf + (size_t)(i0 & ~1u) * 2);   // 16B pair
            bool lo = !(i0 & 1u);
            float f0 = lo ? pv.x : pv.z, f1 = lo ? pv.y : pv.w;
            float c0, c1;
            if (i1 == (i0 ^ 1u)) { c0 = lo ? pv.z : pv.x; c1 = lo ? pv.w : pv.y; }
            else { float2 tv = ((const float2*)tbl)[i1]; c0 = tv.x; c1 = tv.y; }
            a0 += wyz * (wx0 * f0 + ox * c0);
            a1 += wyz * (wx0 * f1 + ox * c1);
        }
    } else {
#pragma unroll
        for (int cr = 0; cr < 8; ++cr) {
            uint32 h = ((cr & 1) ? hx1 : hx0) ^ ((cr & 2) ? hy1 : hy0) ^ ((cr & 4) ? hz1 : hz0);
            uint32 idx = (h & TMASK) + base;
            uint32 dv = ((const uint32*)tbl)[idx];
            float w = ((cr & 1) ? ox : wx0) * ((cr & 2) ? oy : wy0) * ((cr & 4) ? oz : wz0);
            a0 += w * bf2f((ushort16)(dv & 0xffffu));
            a1 += w * bf2f((ushort16)(dv >> 16));
        }
    }
    enc[(size_t)lvl * NPTS + pt] = pack2(a0, a1);
}

// ---------------------------------------------------------------------------
// Kernel B: barrier-free MFMA MLP, R7: sH DELETED — h0/h1/base share the
// R[32..95] work region (each layer reads its input row fully into registers
// before overwriting; DS ops are wave-ordered, rows are wave-private).
// LDS ~69 KB -> 2 blocks/CU = 16 waves/CU (R6's 88 KB -> 1 block/CU was the
// regression). Operand-swapped mfma(W,X) -> D[row=n][col=m] -> packed b64
// writebacks; enc global->fragment direct; finale = 3 mfma on W4 tile.
// Per-wave R[16][136] = [dir 0..31 | work 32..95 | rgb_h 96..127 | pad].
// Dir-encode sits between L2 and Lr to fill the lgkm-wait shadow.
// ---------------------------------------------------------------------------
#define STRY 72
#define STRW0 40
#define STRW12 72
#define STRWR 104
#define STRR 136
#define NWCH (NPTS / 16)        // 32768 wave-chunks

__global__ __launch_bounds__(512) void k_mlp(
    const void* __restrict__ pos,   // for dtype detection only
    const uint32* __restrict__ enc, const void* __restrict__ dirs,
    const void* __restrict__ w0, const void* __restrict__ b0,
    const void* __restrict__ w1, const void* __restrict__ b1,
    const void* __restrict__ w2, const void* __restrict__ b2,
    const void* __restrict__ wr, const void* __restrict__ br,
    const void* __restrict__ wc, const void* __restrict__ bc,
    const void* __restrict__ wd, const void* __restrict__ bd,
    void* __restrict__ out, Freq4 fq)
{
    __shared__ __align__(16) ushort16 sW0[64 * STRW0];
    __shared__ __align__(16) ushort16 sW1[64 * STRW12];
    __shared__ __align__(16) ushort16 sW2[64 * STRW12];
    __shared__ __align__(16) ushort16 sWR[32 * STRWR];
    __shared__ __align__(16) ushort16 sW4[16 * STRWR];
    __shared__ __align__(16) ushort16 sR[8 * 16 * STRR];
    __shared__ __align__(16) float sB0[64], sB1[64], sB2[64], sBR[32], sFB[4];
    __shared__ int sFlag;

    int tid = threadIdx.x;

    if (tid < 64) {
        const ushort16* ph = (const ushort16*)pos;
        float v0 = bf2f(ph[tid]), v1 = bf2f(ph[tid + 64]);
        bool odd = !(fabsf(v0) <= 4.f) || !(fabsf(v1) <= 4.f);
        unsigned long long m = __ballot(odd);
        if (tid == 0) sFlag = (m != 0ull) ? 1 : 0;
    }
    __syncthreads();
    const bool f32 = (sFlag != 0);

    // ---- stage weights once (transpose to [n][k], bf16) ----
    for (int i = tid; i < 2048; i += 512) { int k = i >> 6, n = i & 63; sW0[n * STRW0 + k] = f2bf(ldin(w0, i, f32)); }
    for (int i = tid; i < 4096; i += 512) { int k = i >> 6, n = i & 63; sW1[n * STRW12 + k] = f2bf(ldin(w1, i, f32)); }
    for (int i = tid; i < 4096; i += 512) { int k = i >> 6, n = i & 63; sW2[n * STRW12 + k] = f2bf(ldin(w2, i, f32)); }
    // wr[91][32]: rows 0..26 (dir) -> k=r; rows 27..90 (base) -> k=r+5
    for (int i = tid; i < 2912; i += 512) {
        int r = i >> 5, n = i & 31; int k = (r < 27) ? r : r + 5;
        sWR[n * STRWR + k] = f2bf(ldin(wr, i, f32));
    }
    if (tid < 160) { int n = tid / 5, k = 27 + tid % 5; sWR[n * STRWR + k] = 0; }  // zero pad k=27..31
    // W4[16][96]: k 0..63 = base, k 64..95 = rgb_h; rows 0..2 = wc, row 3 = wd
    for (int i = tid; i < 1536; i += 512) {
        int n = i / 96, j = i % 96;
        float v = 0.f;
        if (n == 3 && j < 64) v = ldin(wd, j, f32);
        else if (n < 3 && j >= 64) v = ldin(wc, (j - 64) * 3 + n, f32);
        sW4[n * STRWR + j] = f2bf(v);
    }
    if (tid < 64) { sB0[tid] = ldin(b0, tid, f32); sB1[tid] = ldin(b1, tid, f32); sB2[tid] = ldin(b2, tid, f32); }
    if (tid < 32) sBR[tid] = ldin(br, tid, f32);
    if (tid < 3) sFB[tid] = ldin(bc, tid, f32);
    if (tid == 3) sFB[3] = ldin(bd, 0, f32);

    int lane = tid & 63, wv = tid >> 6;          // wv in [0,8)
    int colg = lane & 15, quad = lane >> 4;

    ushort16* Rw = &sR[wv * 16 * STRR];

    // zero R pad cols 27..31 once (wave-private, never overwritten)
    if (quad == 3) {
#pragma unroll
        for (int j = 27; j < 32; ++j) Rw[colg * STRR + j] = 0;
    }
    __syncthreads();   // weights staged (only barrier)

    int nwaves = gridDim.x * 8;
    int gw = blockIdx.x * 8 + wv;

    // ---- register prefetch of chunk gw ----
    uint32 eu[4]; float dvv = 0.f;
    {
        int p = gw * 16 + colg;
#pragma unroll
        for (int j = 0; j < 4; ++j) eu[j] = enc[(size_t)(quad * 4 + j) * NPTS + p];
        if (lane < 48) dvv = ldin(dirs, 3 * (gw * 16 + colg) + quad, f32);
    }

    int chunk = gw;
    while (true) {
        int nxtc = chunk + nwaves;
        bool has = nxtc < NWCH;
        uint32 eu2[4] = {0, 0, 0, 0}; float dv2 = 0.f;
        if (has) {
            int p = nxtc * 16 + colg;
#pragma unroll
            for (int j = 0; j < 4; ++j) eu2[j] = enc[(size_t)(quad * 4 + j) * NPTS + p];
            if (lane < 48) dv2 = ldin(dirs, 3 * (nxtc * 16 + colg) + quad, f32);
        }
        int p0 = chunk * 16;

        // ---- L0: relu(enc @ w0 + b0) -> R[32..95] (X-frag direct from global regs) ----
        {
            union { uint32 u[4]; short8 v; } xb;
#pragma unroll
            for (int j = 0; j < 4; ++j) xb.u[j] = eu[j];
#pragma unroll
            for (int nt = 0; nt < 4; ++nt) {
                short8 a = *(const short8*)&sW0[(nt * 16 + colg) * STRW0 + quad * 8];
                f32x4 acc = {0.f, 0.f, 0.f, 0.f};
                acc = __builtin_amdgcn_mfma_f32_16x16x32_bf16(a, xb.v, acc, 0, 0, 0);
                float4 bi = *(const float4*)&sB0[nt * 16 + quad * 4];
                uint2 o;
                o.x = pack2(fmaxf(acc[0] + bi.x, 0.f), fmaxf(acc[1] + bi.y, 0.f));
                o.y = pack2(fmaxf(acc[2] + bi.z, 0.f), fmaxf(acc[3] + bi.w, 0.f));
                *(uint2*)&Rw[colg * STRR + 32 + nt * 16 + quad * 4] = o;
            }
        }
        // ---- L1: relu(h0 @ w1 + b1): read h0 to regs, overwrite R[32..95] ----
        {
            short8 xb0 = *(const short8*)&Rw[colg * STRR + 32 + quad * 8];
            short8 xb1 = *(const short8*)&Rw[colg * STRR + 64 + quad * 8];
#pragma unroll
            for (int nt = 0; nt < 4; ++nt) {
                short8 a0 = *(const short8*)&sW1[(nt * 16 + colg) * STRW12 + quad * 8];
                short8 a1 = *(const short8*)&sW1[(nt * 16 + colg) * STRW12 + 32 + quad * 8];
                f32x4 acc = {0.f, 0.f, 0.f, 0.f};
                acc = __builtin_amdgcn_mfma_f32_16x16x32_bf16(a0, xb0, acc, 0, 0, 0);
                acc = __builtin_amdgcn_mfma_f32_16x16x32_bf16(a1, xb1, acc, 0, 0, 0);
                float4 bi = *(const float4*)&sB1[nt * 16 + quad * 4];
                uint2 o;
                o.x = pack2(fmaxf(acc[0] + bi.x, 0.f), fmaxf(acc[1] + bi.y, 0.f));
                o.y = pack2(fmaxf(acc[2] + bi.z, 0.f), fmaxf(acc[3] + bi.w, 0.f));
                *(uint2*)&Rw[colg * STRR + 32 + nt * 16 + quad * 4] = o;
            }
        }
        // ---- L2: base = h1 @ w2 + b2: read h1 to regs, overwrite R[32..95] ----
        {
            short8 xb0 = *(const short8*)&Rw[colg * STRR + 32 + quad * 8];
            short8 xb1 = *(const short8*)&Rw[colg * STRR + 64 + quad * 8];
#pragma unroll
            for (int nt = 0; nt < 4; ++nt) {
                short8 a0 = *(const short8*)&sW2[(nt * 16 + colg) * STRW12 + quad * 8];
                short8 a1 = *(const short8*)&sW2[(nt * 16 + colg) * STRW12 + 32 + quad * 8];
                f32x4 acc = {0.f, 0.f, 0.f, 0.f};
                acc = __builtin_amdgcn_mfma_f32_16x16x32_bf16(a0, xb0, acc, 0, 0, 0);
                acc = __builtin_amdgcn_mfma_f32_16x16x32_bf16(a1, xb1, acc, 0, 0, 0);
                float4 bi = *(const float4*)&sB2[nt * 16 + quad * 4];
                uint2 o;
                o.x = pack2(acc[0] + bi.x, acc[1] + bi.y);
                o.y = pack2(acc[2] + bi.z, acc[3] + bi.w);
                *(uint2*)&Rw[colg * STRR + 32 + nt * 16 + quad * 4] = o;
            }
        }
        // ---- dir encode (independent VALU work in L2's lgkm shadow) -> R[0..26] ----
        if (lane < 48) {
            ushort16* row = &Rw[colg * STRR];
            float td = 6.28318530717958647692f * dvv;
#pragma unroll
            for (int j = 0; j < 4; ++j) {
                float arg = td * fq.f[j];
                float sv, cv;
                sincosf(arg, &sv, &cv);
                row[quad * 4 + j] = f2bf(sv);
                row[12 + quad * 4 + j] = f2bf(cv);
            }
            row[24 + quad] = f2bf(dvv);
        }
        // ---- Lr: rgb_h = [dir|base] @ wr + br -> R[96..127] (K=96) ----
        {
            short8 xb0 = *(const short8*)&Rw[colg * STRR + quad * 8];
            short8 xb1 = *(const short8*)&Rw[colg * STRR + 32 + quad * 8];
            short8 xb2 = *(const short8*)&Rw[colg * STRR + 64 + quad * 8];
#pragma unroll
            for (int nt = 0; nt < 2; ++nt) {
                short8 a0 = *(const short8*)&sWR[(nt * 16 + colg) * STRWR + quad * 8];
                short8 a1 = *(const short8*)&sWR[(nt * 16 + colg) * STRWR + 32 + quad * 8];
                short8 a2 = *(const short8*)&sWR[(nt * 16 + colg) * STRWR + 64 + quad * 8];
                f32x4 acc = {0.f, 0.f, 0.f, 0.f};
                acc = __builtin_amdgcn_mfma_f32_16x16x32_bf16(a0, xb0, acc, 0, 0, 0);
                acc = __builtin_amdgcn_mfma_f32_16x16x32_bf16(a1, xb1, acc, 0, 0, 0);
                acc = __builtin_amdgcn_mfma_f32_16x16x32_bf16(a2, xb2, acc, 0, 0, 0);
                float4 bi = *(const float4*)&sBR[nt * 16 + quad * 4];
                uint2 o;
                o.x = pack2(acc[0] + bi.x, acc[1] + bi.y);
                o.y = pack2(acc[2] + bi.z, acc[3] + bi.w);
                *(uint2*)&Rw[colg * STRR + 96 + nt * 16 + quad * 4] = o;
            }
        }
        // ---- finale: D' = W4 @ [base|rgb_h]^T; quad0 lane m holds (r,g,b,dd) ----
        {
            short8 xb0 = *(const short8*)&Rw[colg * STRR + 32 + quad * 8];
            short8 xb1 = *(const short8*)&Rw[colg * STRR + 64 + quad * 8];
            short8 xb2 = *(const short8*)&Rw[colg * STRR + 96 + quad * 8];
            short8 a0 = *(const short8*)&sW4[colg * STRWR + quad * 8];
            short8 a1 = *(const short8*)&sW4[colg * STRWR + 32 + quad * 8];
            short8 a2 = *(const short8*)&sW4[colg * STRWR + 64 + quad * 8];
            f32x4 acc = {0.f, 0.f, 0.f, 0.f};
            acc = __builtin_amdgcn_mfma_f32_16x16x32_bf16(a0, xb0, acc, 0, 0, 0);
            acc = __builtin_amdgcn_mfma_f32_16x16x32_bf16(a1, xb1, acc, 0, 0, 0);
            acc = __builtin_amdgcn_mfma_f32_16x16x32_bf16(a2, xb2, acc, 0, 0, 0);
            if (quad == 0) {
                float r0 = acc[0] + sFB[0], r1 = acc[1] + sFB[1], r2 = acc[2] + sFB[2], dd = acc[3] + sFB[3];
                r0 = 1.f / (1.f + expf(-r0));
                r1 = 1.f / (1.f + expf(-r1));
                r2 = 1.f / (1.f + expf(-r2));
                float sp = (dd > 0.f) ? (dd + log1pf(expf(-dd))) : log1pf(expf(dd));
                int pt = p0 + colg;
                if (f32) {
                    float4 o4; o4.x = r0; o4.y = r1; o4.z = r2; o4.w = sp;
                    ((float4*)out)[pt] = o4;
                } else {
                    uint2 o; o.x = pack2(r0, r1); o.y = pack2(r2, sp);
                    ((uint2*)out)[pt] = o;
                }
            }
        }

        if (!has) break;
#pragma unroll
        for (int j = 0; j < 4; ++j) eu[j] = eu2[j];
        dvv = dv2;
        chunk = nxtc;
    }
}

// ---------------------------------------------------------------------------
// Fallback: the round-3 PASSING fully fused kernel (used if ws too small).
// ---------------------------------------------------------------------------
#define FSTRX 104
__global__ __launch_bounds__(256) void k_fused(
    const void* __restrict__ pos, const void* __restrict__ dirs,
    const void* __restrict__ tbl,
    const void* __restrict__ w0, const void* __restrict__ b0,
    const void* __restrict__ w1, const void* __restrict__ b1,
    const void* __restrict__ w2, const void* __restrict__ b2,
    const void* __restrict__ wr, const void* __restrict__ br,
    const void* __restrict__ wc, const void* __restrict__ bc,
    const void* __restrict__ wd, const void* __restrict__ bd,
    void* __restrict__ out, Scal16 sc, Freq4 fq)
{
    __shared__ __align__(16) ushort16 sX[64 * FSTRX];
    __shared__ __align__(16) ushort16 sY[64 * STRY];
    __shared__ __align__(16) ushort16 sW0[64 * STRW0];
    __shared__ __align__(16) ushort16 sW1[64 * STRW12];
    __shared__ __align__(16) ushort16 sW2[64 * STRW12];
    __shared__ __align__(16) ushort16 sWR[32 * STRWR];
    __shared__ float sB0[64], sB1[64], sB2[64], sBR[32];
    __shared__ float sWCf[100];
    __shared__ float sWDf[64];
    __shared__ float sPosF[192];
    __shared__ int sFlag;

    int tid = threadIdx.x;
    if (tid < 64) {
        const ushort16* ph = (const ushort16*)pos;
        float v0 = bf2f(ph[tid]), v1 = bf2f(ph[tid + 64]);
        bool odd = !(fabsf(v0) <= 4.f) || !(fabsf(v1) <= 4.f);
        unsigned long long m = __ballot(odd);
        if (tid == 0) sFlag = (m != 0ull) ? 1 : 0;
    }
    __syncthreads();
    const bool f32 = (sFlag != 0);

    for (int i = tid; i < 2048; i += 256) { int k = i >> 6, n = i & 63; sW0[n * STRW0 + k] = f2bf(ldin(w0, i, f32)); }
    for (int i = tid; i < 4096; i += 256) { int k = i >> 6, n = i & 63; sW1[n * STRW12 + k] = f2bf(ldin(w1, i, f32)); }
    for (int i = tid; i < 4096; i += 256) { int k = i >> 6, n = i & 63; sW2[n * STRW12 + k] = f2bf(ldin(w2, i, f32)); }
    for (int i = tid; i < 2912; i += 256) {
        int r = i >> 5, n = i & 31; int k = (r < 27) ? r : r + 5;
        sWR[n * STRWR + k] = f2bf(ldin(wr, i, f32));
    }
    if (tid < 160) { int n = tid / 5, k = 27 + tid % 5; sWR[n * STRWR + k] = 0; }
    if (tid < 64) { sB0[tid] = ldin(b0, tid, f32); sB1[tid] = ldin(b1, tid, f32);
                    sB2[tid] = ldin(b2, tid, f32); sWDf[tid] = ldin(wd, tid, f32); }
    if (tid < 32) sBR[tid] = ldin(br, tid, f32);
    if (tid < 96) sWCf[tid] = ldin(wc, tid, f32);
    if (tid == 96) { sWCf[96] = ldin(bc, 0, f32); sWCf[97] = ldin(bc, 1, f32);
                     sWCf[98] = ldin(bc, 2, f32); sWCf[99] = ldin(bd, 0, f32); }

    int lane = tid & 63, wv = tid >> 6;
    int colg = lane & 15, quad = lane >> 4;
    int myl = tid & 15;
    float mys = sc.s[myl];
    uint32 mybase = (uint32)myl << LOG2T;

    for (int c = blockIdx.x; c < NPTS / 64; c += gridDim.x) {
        int p0 = c * 64;
        __syncthreads();
        if (tid < 192) sPosF[tid] = ldin(pos, p0 * 3 + tid, f32);
        __syncthreads();
#pragma unroll
        for (int ii = 0; ii < 4; ++ii) {
            int p = (tid >> 4) + 16 * ii;
            float x = sPosF[3 * p], y = sPosF[3 * p + 1], z = sPosF[3 * p + 2];
            float sx = x * mys, sy = y * mys, sz = z * mys;
            float fx = floorf(sx), fy = floorf(sy), fz = floorf(sz);
            float cx = ceilf(sx), cy = ceilf(sy), cz = ceilf(sz);
            float ox = sx - fx, oy = sy - fy, oz = sz - fz;
            uint32 hx0 = (uint32)(int)fx;
            uint32 hx1 = (uint32)(int)cx;
            uint32 hy0 = (uint32)(int)fy * 2654435761u;
            uint32 hy1 = (uint32)(int)cy * 2654435761u;
            uint32 hz0 = (uint32)(int)fz * 805459861u;
            uint32 hz1 = (uint32)(int)cz * 805459861u;
            float wx0 = 1.f - ox, wy0 = 1.f - oy, wz0 = 1.f - oz;
            float a0 = 0.f, a1 = 0.f;
#pragma unroll
            for (int cr = 0; cr < 8; ++cr) {
                uint32 h = ((cr & 1) ? hx1 : hx0) ^ ((cr & 2) ? hy1 : hy0) ^ ((cr & 4) ? hz1 : hz0);
                uint32 idx = (h & TMASK) + mybase;
                float t0, t1;
                if (f32) { float2 tv = ((const float2*)tbl)[idx]; t0 = tv.x; t1 = tv.y; }
                else { uint32 dv = ((const uint32*)tbl)[idx]; t0 = bf2f((ushort16)(dv & 0xffffu)); t1 = bf2f((ushort16)(dv >> 16)); }
                float w = ((cr & 1) ? ox : wx0) * ((cr & 2) ? oy : wy0) * ((cr & 4) ? oz : wz0);
                a0 += w * t0; a1 += w * t1;
            }
            *(uint32*)&sX[p * FSTRX + 2 * myl] = pack2(a0, a1);
        }
        __syncthreads();
        {
            short8 a = *(const short8*)&sX[(wv * 16 + colg) * FSTRX + quad * 8];
#pragma unroll
            for (int nt = 0; nt < 4; ++nt) {
                short8 bb = *(const short8*)&sW0[(nt * 16 + colg) * STRW0 + quad * 8];
                f32x4 acc = {0.f, 0.f, 0.f, 0.f};
                acc = __builtin_amdgcn_mfma_f32_16x16x32_bf16(a, bb, acc, 0, 0, 0);
                float bias = sB0[nt * 16 + colg];
#pragma unroll
                for (int r = 0; r < 4; ++r) {
                    float v = fmaxf(acc[r] + bias, 0.f);
                    sY[(wv * 16 + quad * 4 + r) * STRY + nt * 16 + colg] = f2bf(v);
                }
            }
        }
        __syncthreads();
        {
            short8 a0 = *(const short8*)&sY[(wv * 16 + colg) * STRY + quad * 8];
            short8 a1 = *(const short8*)&sY[(wv * 16 + colg) * STRY + 32 + quad * 8];
#pragma unroll
            for (int nt = 0; nt < 4; ++nt) {
                short8 bb0 = *(const short8*)&sW1[(nt * 16 + colg) * STRW12 + quad * 8];
                short8 bb1 = *(const short8*)&sW1[(nt * 16 + colg) * STRW12 + 32 + quad * 8];
                f32x4 acc = {0.f, 0.f, 0.f, 0.f};
                acc = __builtin_amdgcn_mfma_f32_16x16x32_bf16(a0, bb0, acc, 0, 0, 0);
                acc = __builtin_amdgcn_mfma_f32_16x16x32_bf16(a1, bb1, acc, 0, 0, 0);
                float bias = sB1[nt * 16 + colg];
#pragma unroll
                for (int r = 0; r < 4; ++r) {
                    float v = fmaxf(acc[r] + bias, 0.f);
                    sX[(wv * 16 + quad * 4 + r) * FSTRX + nt * 16 + colg] = f2bf(v);
                }
            }
        }
        __syncthreads();
        {
            short8 a0 = *(const short8*)&sX[(wv * 16 + colg) * FSTRX + quad * 8];
            short8 a1 = *(const short8*)&sX[(wv * 16 + colg) * FSTRX + 32 + quad * 8];
#pragma unroll
            for (int nt = 0; nt < 4; ++nt) {
                short8 bb0 = *(const short8*)&sW2[(nt * 16 + colg) * STRW12 + quad * 8];
                short8 bb1 = *(const short8*)&sW2[(nt * 16 + colg) * STRW12 + 32 + quad * 8];
                f32x4 acc = {0.f, 0.f, 0.f, 0.f};
                acc = __builtin_amdgcn_mfma_f32_16x16x32_bf16(a0, bb0, acc, 0, 0, 0);
                acc = __builtin_amdgcn_mfma_f32_16x16x32_bf16(a1, bb1, acc, 0, 0, 0);
                float bias = sB2[nt * 16 + colg];
#pragma unroll
                for (int r = 0; r < 4; ++r) {
                    sY[(wv * 16 + quad * 4 + r) * STRY + nt * 16 + colg] = f2bf(acc[r] + bias);
                }
            }
        }
        if (tid < 192) {
            int p = tid / 3, i2 = tid % 3;
            float dvv = ldin(dirs, 3 * (p0 + p) + i2, f32);
            ushort16* row = &sX[p * FSTRX + 64];
            float td = 6.28318530717958647692f * dvv;
#pragma unroll
            for (int j = 0; j < 4; ++j) {
                float arg = td * fq.f[j];
                float sv, cv;
                sincosf(arg, &sv, &cv);
                row[i2 * 4 + j] = f2bf(sv);
                row[12 + i2 * 4 + j] = f2bf(cv);
            }
            row[24 + i2] = f2bf(dvv);
        } else {
            int p = tid - 192;
            ushort16* row = &sX[p * FSTRX + 64];
#pragma unroll
            for (int j = 27; j < 32; ++j) row[j] = 0;
        }
        __syncthreads();
        {
            short8 a0 = *(const short8*)&sX[(wv * 16 + colg) * FSTRX + 64 + quad * 8];
            short8 a1 = *(const short8*)&sY[(wv * 16 + colg) * STRY + quad * 8];
            short8 a2 = *(const short8*)&sY[(wv * 16 + colg) * STRY + 32 + quad * 8];
#pragma unroll
            for (int nt = 0; nt < 2; ++nt) {
                short8 bb0 = *(const short8*)&sWR[(nt * 16 + colg) * STRWR + quad * 8];
                short8 bb1 = *(const short8*)&sWR[(nt * 16 + colg) * STRWR + 32 + quad * 8];
                short8 bb2 = *(const short8*)&sWR[(nt * 16 + colg) * STRWR + 64 + quad * 8];
                f32x4 acc = {0.f, 0.f, 0.f, 0.f};
                acc = __builtin_amdgcn_mfma_f32_16x16x32_bf16(a0, bb0, acc, 0, 0, 0);
                acc = __builtin_amdgcn_mfma_f32_16x16x32_bf16(a1, bb1, acc, 0, 0, 0);
                acc = __builtin_amdgcn_mfma_f32_16x16x32_bf16(a2, bb2, acc, 0, 0, 0);
                float bias = sBR[nt * 16 + colg];
#pragma unroll
                for (int r = 0; r < 4; ++r) {
                    sX[(wv * 16 + quad * 4 + r) * FSTRX + nt * 16 + colg] = f2bf(acc[r] + bias);
                }
            }
        }
        __syncthreads();
        if (tid < 64) {
            int pt = p0 + tid;
            float r0 = 0.f, r1 = 0.f, r2 = 0.f, dd = 0.f;
            const ushort16* hx = &sX[tid * FSTRX];
            const ushort16* hb = &sY[tid * STRY];
#pragma unroll
            for (int k = 0; k < 32; ++k) {
                float hv = bf2f(hx[k]);
                r0 += hv * sWCf[k * 3 + 0];
                r1 += hv * sWCf[k * 3 + 1];
                r2 += hv * sWCf[k * 3 + 2];
            }
#pragma unroll
            for (int k = 0; k < 64; ++k) dd += bf2f(hb[k]) * sWDf[k];
            r0 += sWCf[96]; r1 += sWCf[97]; r2 += sWCf[98]; dd += sWCf[99];
            r0 = 1.f / (1.f + expf(-r0));
            r1 = 1.f / (1.f + expf(-r1));
            r2 = 1.f / (1.f + expf(-r2));
            float sp = (dd > 0.f) ? (dd + log1pf(expf(-dd))) : log1pf(expf(dd));
            if (f32) {
                float4 o4; o4.x = r0; o4.y = r1; o4.z = r2; o4.w = sp;
                ((float4*)out)[pt] = o4;
            } else {
                uint2 o;
                o.x = pack2(r0, r1); o.y = pack2(r2, sp);
                ((uint2*)out)[pt] = o;
            }
        }
    }
}

// ---------------------------------------------------------------------------
extern "C" void kernel_launch(void* const* d_in, const int* in_sizes, int n_in,
                              void* d_out, int out_size, void* d_ws, size_t ws_size,
                              hipStream_t stream) {
    (void)in_sizes; (void)n_in; (void)out_size;

    // SCALINGS with identical libm double math to numpy
    Scal16 sc;
    double g = exp((log(1024.0) - log(16.0)) / 15.0);
    for (int l = 0; l < 16; ++l) sc.s[l] = (float)floor(16.0 * pow(g, (double)l));

    // freqs = 2 ** float32(linspace(0,4,4))
    Freq4 fq;
    float lv[4] = {0.f, 4.f / 3.f, 8.f / 3.f, 4.f};
    for (int j = 0; j < 4; ++j) fq.f[j] = (float)pow(2.0, (double)lv[j]);

    const size_t enc_bytes = (size_t)16 * NPTS * 4;   // 32 MiB packed-bf16 enc
    if (ws_size >= enc_bytes) {
        uint32* enc = (uint32*)d_ws;
        // single launch, 2 phases x 8 XCD-pinned levels + x-corner pairing
        k_hash<<<dim3(2 * 8 * NPTS / 256), dim3(256), 0, stream>>>(d_in[0], d_in[2], enc, sc);
        k_mlp<<<dim3(512), dim3(512), 0, stream>>>(
            d_in[0], enc, d_in[1], d_in[3], d_in[4], d_in[5], d_in[6], d_in[7],
            d_in[8], d_in[9], d_in[10], d_in[11], d_in[12], d_in[13], d_in[14],
            d_out, fq);
    } else {
        k_fused<<<dim3(512), dim3(256), 0, stream>>>(
            d_in[0], d_in[1], d_in[2], d_in[3], d_in[4], d_in[5], d_in[6], d_in[7],
            d_in[8], d_in[9], d_in[10], d_in[11], d_in[12], d_in[13], d_in[14],
            d_out, sc, fq);
    }
}

// Round 8
// 373.888 us; speedup vs baseline: 1.0229x; 1.0229x over previous
//
#include <hip/hip_runtime.h>
#include <math.h>

#define NPTS 524288
#define LOG2T 19
#define TSIZE (1u << LOG2T)
#define TMASK (TSIZE - 1u)

typedef unsigned int uint32;
typedef unsigned short ushort16;

typedef __attribute__((ext_vector_type(8))) short short8;
typedef __attribute__((ext_vector_type(4))) float f32x4;

__device__ __forceinline__ float bf2f(ushort16 u) {
    union { uint32 i; float f; } v; v.i = ((uint32)u) << 16; return v.f;
}
__device__ __forceinline__ ushort16 f2bf(float f) {
    union { float f; uint32 i; } v; v.f = f;
    uint32 r = v.i + 0x7fffu + ((v.i >> 16) & 1u);   // RNE
    return (ushort16)(r >> 16);
}
__device__ __forceinline__ uint32 pack2(float a, float b) {
    return (uint32)f2bf(a) | ((uint32)f2bf(b) << 16);
}
// dtype-flexible scalar load: fp32 or bf16 per runtime flag (block-uniform)
__device__ __forceinline__ float ldin(const void* p, int i, bool f32) {
    return f32 ? ((const float*)p)[i] : bf2f(((const ushort16*)p)[i]);
}

struct Scal16 { float s[16]; };
struct Freq4  { float f[4]; };

// ---------------------------------------------------------------------------
// Kernel A (unchanged, 207 us measured): level-major hash encode, single
// launch, 2 phases x 8 levels; lvl = phase*8 + (blockIdx&7) pins each level's
// 4 MiB fp32 sub-table to one XCD's L2. x-corner pairing: when idx_ce ==
// idx_fl^1 (ix even, exactly the pairable 50%), one aligned 16B load serves
// both corners (~6 L2 requests per (pt,lvl)). Measured ~82% of the per-XCD
// L2-request ceiling (13 of ~16 req/cyc/XCD) — near-roofline for 8 gathers.
// enc[lvl*NPTS+pt] = packed bf16 (feat0 | feat1<<16)
// ---------------------------------------------------------------------------
__global__ __launch_bounds__(256) void k_hash(const void* __restrict__ pos,
                                              const void* __restrict__ tbl,
                                              uint32* __restrict__ enc,
                                              Scal16 sc) {
    __shared__ int sFlag;
    int tid = threadIdx.x;
    if (tid < 64) {   // dtype detect: positions in [0,1); bf16-misread of fp32 -> garbage
        const ushort16* ph = (const ushort16*)pos;
        float v0 = bf2f(ph[tid]), v1 = bf2f(ph[tid + 64]);
        bool odd = !(fabsf(v0) <= 4.f) || !(fabsf(v1) <= 4.f);
        unsigned long long m = __ballot(odd);
        if (tid == 0) sFlag = (m != 0ull) ? 1 : 0;
    }
    __syncthreads();
    const bool f32 = (sFlag != 0);

    int lvl = ((blockIdx.x >> 14) << 3) + (blockIdx.x & 7);
    int pt = ((blockIdx.x >> 3) & 2047) * 256 + tid;

    float s = sc.s[lvl];
    float x = ldin(pos, 3 * pt, f32), y = ldin(pos, 3 * pt + 1, f32), z = ldin(pos, 3 * pt + 2, f32);
    float sx = x * s, sy = y * s, sz = z * s;
    float fx = floorf(sx), fy = floorf(sy), fz = floorf(sz);
    float cx = ceilf(sx), cy = ceilf(sy), cz = ceilf(sz);   // ceil, NOT floor+1 (matches ref)
    float ox = sx - fx, oy = sy - fy, oz = sz - fz;
    uint32 hx0 = (uint32)(int)fx;                       // prime[0] = 1
    uint32 hx1 = (uint32)(int)cx;
    uint32 hy0 = (uint32)(int)fy * 2654435761u;
    uint32 hy1 = (uint32)(int)cy * 2654435761u;
    uint32 hz0 = (uint32)(int)fz * 805459861u;
    uint32 hz1 = (uint32)(int)cz * 805459861u;
    uint32 base = (uint32)lvl << LOG2T;
    float wx0 = 1.f - ox, wy0 = 1.f - oy, wz0 = 1.f - oz;

    float a0 = 0.f, a1 = 0.f;
    if (f32) {
        const float* tf = (const float*)tbl;
#pragma unroll
        for (int yz = 0; yz < 4; ++yz) {
            uint32 m = ((yz & 1) ? hy1 : hy0) ^ ((yz & 2) ? hz1 : hz0);
            float wyz = ((yz & 1) ? oy : wy0) * ((yz & 2) ? oz : wz0);
            uint32 i0 = ((hx0 ^ m) & TMASK) + base;
            uint32 i1 = ((hx1 ^ m) & TMASK) + base;
            float4 pv = *(const float4*)(tf + (size_t)(i0 & ~1u) * 2);   // 16B pair
            bool lo = !(i0 & 1u);
            float f0 = lo ? pv.x : pv.z, f1 = lo ? pv.y : pv.w;
            float c0, c1;
            if (i1 == (i0 ^ 1u)) { c0 = lo ? pv.z : pv.x; c1 = lo ? pv.w : pv.y; }
            else { float2 tv = ((const float2*)tbl)[i1]; c0 = tv.x; c1 = tv.y; }
            a0 += wyz * (wx0 * f0 + ox * c0);
            a1 += wyz * (wx0 * f1 + ox * c1);
        }
    } else {
#pragma unroll
        for (int cr = 0; cr < 8; ++cr) {
            uint32 h = ((cr & 1) ? hx1 : hx0) ^ ((cr & 2) ? hy1 : hy0) ^ ((cr & 4) ? hz1 : hz0);
            uint32 idx = (h & TMASK) + base;
            uint32 dv = ((const uint32*)tbl)[idx];
            float w = ((cr & 1) ? ox : wx0) * ((cr & 2) ? oy : wy0) * ((cr & 4) ? oz : wz0);
            a0 += w * bf2f((ushort16)(dv & 0xffffu));
            a1 += w * bf2f((ushort16)(dv >> 16));
        }
    }
    enc[(size_t)lvl * NPTS + pt] = pack2(a0, a1);
}

// ---------------------------------------------------------------------------
// Kernel B: EXACT R5 structure (measured 115 us — the best of 3 mlp variants)
// with ONE change: the scalar 160-MAC finale (R5's largest VALU term) is
// replaced by the per-wave W4-MFMA finale proven correct in R6/R7, and the
// now-unneeded third barrier is dropped (finale reads only own-wave rows).
// 512 thr / 8 waves, 128 pts/iter, wave w owns 16-pt M-tile w. Buffers:
//   sX[128][100]: enc(0..31)->h1(0..63), dirs(64..95), rgb_h(0..31)
//   sY[128][72] : h0(0..63)->base(0..63)
// Weights transposed [n][k] bf16; layouts (verified gfx950):
// A: m=lane&15,k=quad*8+j; B^T row n=lane&15; D: col=lane&15,row=quad*4+reg.
// ---------------------------------------------------------------------------
#define STRY 72
#define STRW0 40
#define STRW12 72
#define STRWR 104
#define MSTRX 100
#define PPI 128                 // points per iteration
#define NIT (NPTS / PPI)

__global__ __launch_bounds__(512) void k_mlp(
    const void* __restrict__ pos,   // for dtype detection only
    const uint32* __restrict__ enc, const void* __restrict__ dirs,
    const void* __restrict__ w0, const void* __restrict__ b0,
    const void* __restrict__ w1, const void* __restrict__ b1,
    const void* __restrict__ w2, const void* __restrict__ b2,
    const void* __restrict__ wr, const void* __restrict__ br,
    const void* __restrict__ wc, const void* __restrict__ bc,
    const void* __restrict__ wd, const void* __restrict__ bd,
    void* __restrict__ out, Freq4 fq)
{
    __shared__ __align__(16) ushort16 sX[PPI * MSTRX];
    __shared__ __align__(16) ushort16 sY[PPI * STRY];
    __shared__ __align__(16) ushort16 sW0[64 * STRW0];
    __shared__ __align__(16) ushort16 sW1[64 * STRW12];
    __shared__ __align__(16) ushort16 sW2[64 * STRW12];
    __shared__ __align__(16) ushort16 sWR[32 * STRWR];
    __shared__ __align__(16) ushort16 sW4[16 * STRWR];
    __shared__ __align__(16) float sB0[64], sB1[64], sB2[64], sBR[32], sFB[4];
    __shared__ int sFlag;

    int tid = threadIdx.x;

    if (tid < 64) {
        const ushort16* ph = (const ushort16*)pos;
        float v0 = bf2f(ph[tid]), v1 = bf2f(ph[tid + 64]);
        bool odd = !(fabsf(v0) <= 4.f) || !(fabsf(v1) <= 4.f);
        unsigned long long m = __ballot(odd);
        if (tid == 0) sFlag = (m != 0ull) ? 1 : 0;
    }
    __syncthreads();
    const bool f32 = (sFlag != 0);

    // ---- stage weights once (transpose to [n][k], bf16) ----
    for (int i = tid; i < 2048; i += 512) { int k = i >> 6, n = i & 63; sW0[n * STRW0 + k] = f2bf(ldin(w0, i, f32)); }
    for (int i = tid; i < 4096; i += 512) { int k = i >> 6, n = i & 63; sW1[n * STRW12 + k] = f2bf(ldin(w1, i, f32)); }
    for (int i = tid; i < 4096; i += 512) { int k = i >> 6, n = i & 63; sW2[n * STRW12 + k] = f2bf(ldin(w2, i, f32)); }
    // wr[91][32]: rows 0..26 (dir) -> k=r; rows 27..90 (base) -> k=r+5
    for (int i = tid; i < 2912; i += 512) {
        int r = i >> 5, n = i & 31; int k = (r < 27) ? r : r + 5;
        sWR[n * STRWR + k] = f2bf(ldin(wr, i, f32));
    }
    if (tid < 160) { int n = tid / 5, k = 27 + tid % 5; sWR[n * STRWR + k] = 0; }  // zero pad k=27..31
    // W4[16][96]: k 0..63 = base, k 64..95 = rgb_h; rows 0..2 = wc, row 3 = wd
    for (int i = tid; i < 1536; i += 512) {
        int n = i / 96, j = i % 96;
        float v = 0.f;
        if (n == 3 && j < 64) v = ldin(wd, j, f32);
        else if (n < 3 && j >= 64) v = ldin(wc, (j - 64) * 3 + n, f32);
        sW4[n * STRWR + j] = f2bf(v);
    }
    if (tid < 64) { sB0[tid] = ldin(b0, tid, f32); sB1[tid] = ldin(b1, tid, f32); sB2[tid] = ldin(b2, tid, f32); }
    if (tid < 32) sBR[tid] = ldin(br, tid, f32);
    if (tid < 3) sFB[tid] = ldin(bc, tid, f32);
    if (tid == 3) sFB[3] = ldin(bd, 0, f32);

    int lane = tid & 63, wv = tid >> 6;          // wv in [0,8)
    int colg = lane & 15, quad = lane >> 4;

    for (int c = blockIdx.x; c < NIT; c += gridDim.x) {
        int p0 = c * PPI;
        __syncthreads();   // B1: prev iteration finale reads done (covers weight staging on iter 0)

        // ---- stage enc -> sX cols 0..31 (2048 dwords, coalesced per level) ----
        for (int i = tid; i < 2048; i += 512) {
            int l = i >> 7, p = i & 127;
            *(uint32*)&sX[p * MSTRX + 2 * l] = enc[(size_t)l * NPTS + p0 + p];
        }
        // ---- NeRF dir encode -> sX cols 64..95 (384 (pt,axis) jobs) ----
        if (tid < 384) {
            int p = tid / 3, i2 = tid % 3;
            float dvv = ldin(dirs, 3 * (p0 + p) + i2, f32);
            ushort16* row = &sX[p * MSTRX + 64];
            float td = 6.28318530717958647692f * dvv;
#pragma unroll
            for (int j = 0; j < 4; ++j) {
                float arg = td * fq.f[j];
                float sv, cv;
                sincosf(arg, &sv, &cv);
                row[i2 * 4 + j] = f2bf(sv);
                row[12 + i2 * 4 + j] = f2bf(cv);
            }
            row[24 + i2] = f2bf(dvv);
        } else {
            int p = tid - 384;   // 128 threads zero cols 91..95
            ushort16* row = &sX[p * MSTRX + 64];
#pragma unroll
            for (int j = 27; j < 32; ++j) row[j] = 0;
        }
        __syncthreads();   // B2: enc + dir staged

        // ---- L0: relu(enc @ w0 + b0) -> sY[0..63]  (rows wave-private from here) ----
        {
            short8 a = *(const short8*)&sX[(wv * 16 + colg) * MSTRX + quad * 8];
#pragma unroll
            for (int nt = 0; nt < 4; ++nt) {
                short8 bb = *(const short8*)&sW0[(nt * 16 + colg) * STRW0 + quad * 8];
                f32x4 acc = {0.f, 0.f, 0.f, 0.f};
                acc = __builtin_amdgcn_mfma_f32_16x16x32_bf16(a, bb, acc, 0, 0, 0);
                float bias = sB0[nt * 16 + colg];
#pragma unroll
                for (int r = 0; r < 4; ++r) {
                    float v = fmaxf(acc[r] + bias, 0.f);
                    sY[(wv * 16 + quad * 4 + r) * STRY + nt * 16 + colg] = f2bf(v);
                }
            }
        }
        // ---- L1: relu(h0 @ w1 + b1) -> sX[0..63] ----
        {
            short8 a0 = *(const short8*)&sY[(wv * 16 + colg) * STRY + quad * 8];
            short8 a1 = *(const short8*)&sY[(wv * 16 + colg) * STRY + 32 + quad * 8];
#pragma unroll
            for (int nt = 0; nt < 4; ++nt) {
                short8 bb0 = *(const short8*)&sW1[(nt * 16 + colg) * STRW12 + quad * 8];
                short8 bb1 = *(const short8*)&sW1[(nt * 16 + colg) * STRW12 + 32 + quad * 8];
                f32x4 acc = {0.f, 0.f, 0.f, 0.f};
                acc = __builtin_amdgcn_mfma_f32_16x16x32_bf16(a0, bb0, acc, 0, 0, 0);
                acc = __builtin_amdgcn_mfma_f32_16x16x32_bf16(a1, bb1, acc, 0, 0, 0);
                float bias = sB1[nt * 16 + colg];
#pragma unroll
                for (int r = 0; r < 4; ++r) {
                    float v = fmaxf(acc[r] + bias, 0.f);
                    sX[(wv * 16 + quad * 4 + r) * MSTRX + nt * 16 + colg] = f2bf(v);
                }
            }
        }
        // ---- L2: base = h1 @ w2 + b2 -> sY[0..63] ----
        {
            short8 a0 = *(const short8*)&sX[(wv * 16 + colg) * MSTRX + quad * 8];
            short8 a1 = *(const short8*)&sX[(wv * 16 + colg) * MSTRX + 32 + quad * 8];
#pragma unroll
            for (int nt = 0; nt < 4; ++nt) {
                short8 bb0 = *(const short8*)&sW2[(nt * 16 + colg) * STRW12 + quad * 8];
                short8 bb1 = *(const short8*)&sW2[(nt * 16 + colg) * STRW12 + 32 + quad * 8];
                f32x4 acc = {0.f, 0.f, 0.f, 0.f};
                acc = __builtin_amdgcn_mfma_f32_16x16x32_bf16(a0, bb0, acc, 0, 0, 0);
                acc = __builtin_amdgcn_mfma_f32_16x16x32_bf16(a1, bb1, acc, 0, 0, 0);
                float bias = sB2[nt * 16 + colg];
#pragma unroll
                for (int r = 0; r < 4; ++r) {   // linear out
                    sY[(wv * 16 + quad * 4 + r) * STRY + nt * 16 + colg] = f2bf(acc[r] + bias);
                }
            }
        }
        // ---- Lr: rgb_h = [enc_dir | base] @ wr + br -> sX[0..31] (K=96) ----
        {
            short8 a0 = *(const short8*)&sX[(wv * 16 + colg) * MSTRX + 64 + quad * 8];
            short8 a1 = *(const short8*)&sY[(wv * 16 + colg) * STRY + quad * 8];
            short8 a2 = *(const short8*)&sY[(wv * 16 + colg) * STRY + 32 + quad * 8];
#pragma unroll
            for (int nt = 0; nt < 2; ++nt) {
                short8 bb0 = *(const short8*)&sWR[(nt * 16 + colg) * STRWR + quad * 8];
                short8 bb1 = *(const short8*)&sWR[(nt * 16 + colg) * STRWR + 32 + quad * 8];
                short8 bb2 = *(const short8*)&sWR[(nt * 16 + colg) * STRWR + 64 + quad * 8];
                f32x4 acc = {0.f, 0.f, 0.f, 0.f};
                acc = __builtin_amdgcn_mfma_f32_16x16x32_bf16(a0, bb0, acc, 0, 0, 0);
                acc = __builtin_amdgcn_mfma_f32_16x16x32_bf16(a1, bb1, acc, 0, 0, 0);
                acc = __builtin_amdgcn_mfma_f32_16x16x32_bf16(a2, bb2, acc, 0, 0, 0);
                float bias = sBR[nt * 16 + colg];
#pragma unroll
                for (int r = 0; r < 4; ++r) {
                    sX[(wv * 16 + quad * 4 + r) * MSTRX + nt * 16 + colg] = f2bf(acc[r] + bias);
                }
            }
        }
        // ---- finale (R6/R7-proven): D' = W4 @ [base|rgb_h]^T, per-wave rows;
        //      quad-0 lane m holds (r,g,b,dd) for point wv*16+m ----
        {
            int m = wv * 16 + colg;
            short8 xb0 = *(const short8*)&sY[m * STRY + quad * 8];        // base 0..31
            short8 xb1 = *(const short8*)&sY[m * STRY + 32 + quad * 8];   // base 32..63
            short8 xb2 = *(const short8*)&sX[m * MSTRX + quad * 8];       // rgb_h 0..31
            short8 a0 = *(const short8*)&sW4[colg * STRWR + quad * 8];
            short8 a1 = *(const short8*)&sW4[colg * STRWR + 32 + quad * 8];
            short8 a2 = *(const short8*)&sW4[colg * STRWR + 64 + quad * 8];
            f32x4 acc = {0.f, 0.f, 0.f, 0.f};
            acc = __builtin_amdgcn_mfma_f32_16x16x32_bf16(a0, xb0, acc, 0, 0, 0);
            acc = __builtin_amdgcn_mfma_f32_16x16x32_bf16(a1, xb1, acc, 0, 0, 0);
            acc = __builtin_amdgcn_mfma_f32_16x16x32_bf16(a2, xb2, acc, 0, 0, 0);
            if (quad == 0) {
                float r0 = acc[0] + sFB[0], r1 = acc[1] + sFB[1], r2 = acc[2] + sFB[2], dd = acc[3] + sFB[3];
                r0 = 1.f / (1.f + expf(-r0));
                r1 = 1.f / (1.f + expf(-r1));
                r2 = 1.f / (1.f + expf(-r2));
                float sp = (dd > 0.f) ? (dd + log1pf(expf(-dd))) : log1pf(expf(dd));
                int pt = p0 + wv * 16 + colg;
                if (f32) {
                    float4 o4; o4.x = r0; o4.y = r1; o4.z = r2; o4.w = sp;
                    ((float4*)out)[pt] = o4;
                } else {
                    uint2 o; o.x = pack2(r0, r1); o.y = pack2(r2, sp);
                    ((uint2*)out)[pt] = o;
                }
            }
        }
        // no B3: finale reads only own-wave rows; B1 protects next staging
    }
}

// ---------------------------------------------------------------------------
// Fallback: the round-3 PASSING fully fused kernel (used if ws too small).
// ---------------------------------------------------------------------------
#define FSTRX 104
__global__ __launch_bounds__(256) void k_fused(
    const void* __restrict__ pos, const void* __restrict__ dirs,
    const void* __restrict__ tbl,
    const void* __restrict__ w0, const void* __restrict__ b0,
    const void* __restrict__ w1, const void* __restrict__ b1,
    const void* __restrict__ w2, const void* __restrict__ b2,
    const void* __restrict__ wr, const void* __restrict__ br,
    const void* __restrict__ wc, const void* __restrict__ bc,
    const void* __restrict__ wd, const void* __restrict__ bd,
    void* __restrict__ out, Scal16 sc, Freq4 fq)
{
    __shared__ __align__(16) ushort16 sX[64 * FSTRX];
    __shared__ __align__(16) ushort16 sY[64 * STRY];
    __shared__ __align__(16) ushort16 sW0[64 * STRW0];
    __shared__ __align__(16) ushort16 sW1[64 * STRW12];
    __shared__ __align__(16) ushort16 sW2[64 * STRW12];
    __shared__ __align__(16) ushort16 sWR[32 * STRWR];
    __shared__ float sB0[64], sB1[64], sB2[64], sBR[32];
    __shared__ float sWCf[100];
    __shared__ float sWDf[64];
    __shared__ float sPosF[192];
    __shared__ int sFlag;

    int tid = threadIdx.x;
    if (tid < 64) {
        const ushort16* ph = (const ushort16*)pos;
        float v0 = bf2f(ph[tid]), v1 = bf2f(ph[tid + 64]);
        bool odd = !(fabsf(v0) <= 4.f) || !(fabsf(v1) <= 4.f);
        unsigned long long m = __ballot(odd);
        if (tid == 0) sFlag = (m != 0ull) ? 1 : 0;
    }
    __syncthreads();
    const bool f32 = (sFlag != 0);

    for (int i = tid; i < 2048; i += 256) { int k = i >> 6, n = i & 63; sW0[n * STRW0 + k] = f2bf(ldin(w0, i, f32)); }
    for (int i = tid; i < 4096; i += 256) { int k = i >> 6, n = i & 63; sW1[n * STRW12 + k] = f2bf(ldin(w1, i, f32)); }
    for (int i = tid; i < 4096; i += 256) { int k = i >> 6, n = i & 63; sW2[n * STRW12 + k] = f2bf(ldin(w2, i, f32)); }
    for (int i = tid; i < 2912; i += 256) {
        int r = i >> 5, n = i & 31; int k = (r < 27) ? r : r + 5;
        sWR[n * STRWR + k] = f2bf(ldin(wr, i, f32));
    }
    if (tid < 160) { int n = tid / 5, k = 27 + tid % 5; sWR[n * STRWR + k] = 0; }
    if (tid < 64) { sB0[tid] = ldin(b0, tid, f32); sB1[tid] = ldin(b1, tid, f32);
                    sB2[tid] = ldin(b2, tid, f32); sWDf[tid] = ldin(wd, tid, f32); }
    if (tid < 32) sBR[tid] = ldin(br, tid, f32);
    if (tid < 96) sWCf[tid] = ldin(wc, tid, f32);
    if (tid == 96) { sWCf[96] = ldin(bc, 0, f32); sWCf[97] = ldin(bc, 1, f32);
                     sWCf[98] = ldin(bc, 2, f32); sWCf[99] = ldin(bd, 0, f32); }

    int lane = tid & 63, wv = tid >> 6;
    int colg = lane & 15, quad = lane >> 4;
    int myl = tid & 15;
    float mys = sc.s[myl];
    uint32 mybase = (uint32)myl << LOG2T;

    for (int c = blockIdx.x; c < NPTS / 64; c += gridDim.x) {
        int p0 = c * 64;
        __syncthreads();
        if (tid < 192) sPosF[tid] = ldin(pos, p0 * 3 + tid, f32);
        __syncthreads();
#pragma unroll
        for (int ii = 0; ii < 4; ++ii) {
            int p = (tid >> 4) + 16 * ii;
            float x = sPosF[3 * p], y = sPosF[3 * p + 1], z = sPosF[3 * p + 2];
            float sx = x * mys, sy = y * mys, sz = z * mys;
            float fx = floorf(sx), fy = floorf(sy), fz = floorf(sz);
            float cx = ceilf(sx), cy = ceilf(sy), cz = ceilf(sz);
            float ox = sx - fx, oy = sy - fy, oz = sz - fz;
            uint32 hx0 = (uint32)(int)fx;
            uint32 hx1 = (uint32)(int)cx;
            uint32 hy0 = (uint32)(int)fy * 2654435761u;
            uint32 hy1 = (uint32)(int)cy * 2654435761u;
            uint32 hz0 = (uint32)(int)fz * 805459861u;
            uint32 hz1 = (uint32)(int)cz * 805459861u;
            float wx0 = 1.f - ox, wy0 = 1.f - oy, wz0 = 1.f - oz;
            float a0 = 0.f, a1 = 0.f;
#pragma unroll
            for (int cr = 0; cr < 8; ++cr) {
                uint32 h = ((cr & 1) ? hx1 : hx0) ^ ((cr & 2) ? hy1 : hy0) ^ ((cr & 4) ? hz1 : hz0);
                uint32 idx = (h & TMASK) + mybase;
                float t0, t1;
                if (f32) { float2 tv = ((const float2*)tbl)[idx]; t0 = tv.x; t1 = tv.y; }
                else { uint32 dv = ((const uint32*)tbl)[idx]; t0 = bf2f((ushort16)(dv & 0xffffu)); t1 = bf2f((ushort16)(dv >> 16)); }
                float w = ((cr & 1) ? ox : wx0) * ((cr & 2) ? oy : wy0) * ((cr & 4) ? oz : wz0);
                a0 += w * t0; a1 += w * t1;
            }
            *(uint32*)&sX[p * FSTRX + 2 * myl] = pack2(a0, a1);
        }
        __syncthreads();
        {
            short8 a = *(const short8*)&sX[(wv * 16 + colg) * FSTRX + quad * 8];
#pragma unroll
            for (int nt = 0; nt < 4; ++nt) {
                short8 bb = *(const short8*)&sW0[(nt * 16 + colg) * STRW0 + quad * 8];
                f32x4 acc = {0.f, 0.f, 0.f, 0.f};
                acc = __builtin_amdgcn_mfma_f32_16x16x32_bf16(a, bb, acc, 0, 0, 0);
                float bias = sB0[nt * 16 + colg];
#pragma unroll
                for (int r = 0; r < 4; ++r) {
                    float v = fmaxf(acc[r] + bias, 0.f);
                    sY[(wv * 16 + quad * 4 + r) * STRY + nt * 16 + colg] = f2bf(v);
                }
            }
        }
        __syncthreads();
        {
            short8 a0 = *(const short8*)&sY[(wv * 16 + colg) * STRY + quad * 8];
            short8 a1 = *(const short8*)&sY[(wv * 16 + colg) * STRY + 32 + quad * 8];
#pragma unroll
            for (int nt = 0; nt < 4; ++nt) {
                short8 bb0 = *(const short8*)&sW1[(nt * 16 + colg) * STRW12 + quad * 8];
                short8 bb1 = *(const short8*)&sW1[(nt * 16 + colg) * STRW12 + 32 + quad * 8];
                f32x4 acc = {0.f, 0.f, 0.f, 0.f};
                acc = __builtin_amdgcn_mfma_f32_16x16x32_bf16(a0, bb0, acc, 0, 0, 0);
                acc = __builtin_amdgcn_mfma_f32_16x16x32_bf16(a1, bb1, acc, 0, 0, 0);
                float bias = sB1[nt * 16 + colg];
#pragma unroll
                for (int r = 0; r < 4; ++r) {
                    float v = fmaxf(acc[r] + bias, 0.f);
                    sX[(wv * 16 + quad * 4 + r) * FSTRX + nt * 16 + colg] = f2bf(v);
                }
            }
        }
        __syncthreads();
        {
            short8 a0 = *(const short8*)&sX[(wv * 16 + colg) * FSTRX + quad * 8];
            short8 a1 = *(const short8*)&sX[(wv * 16 + colg) * FSTRX + 32 + quad * 8];
#pragma unroll
            for (int nt = 0; nt < 4; ++nt) {
                short8 bb0 = *(const short8*)&sW2[(nt * 16 + colg) * STRW12 + quad * 8];
                short8 bb1 = *(const short8*)&sW2[(nt * 16 + colg) * STRW12 + 32 + quad * 8];
                f32x4 acc = {0.f, 0.f, 0.f, 0.f};
                acc = __builtin_amdgcn_mfma_f32_16x16x32_bf16(a0, bb0, acc, 0, 0, 0);
                acc = __builtin_amdgcn_mfma_f32_16x16x32_bf16(a1, bb1, acc, 0, 0, 0);
                float bias = sB2[nt * 16 + colg];
#pragma unroll
                for (int r = 0; r < 4; ++r) {
                    sY[(wv * 16 + quad * 4 + r) * STRY + nt * 16 + colg] = f2bf(acc[r] + bias);
                }
            }
        }
        if (tid < 192) {
            int p = tid / 3, i2 = tid % 3;
            float dvv = ldin(dirs, 3 * (p0 + p) + i2, f32);
            ushort16* row = &sX[p * FSTRX + 64];
            float td = 6.28318530717958647692f * dvv;
#pragma unroll
            for (int j = 0; j < 4; ++j) {
                float arg = td * fq.f[j];
                float sv, cv;
                sincosf(arg, &sv, &cv);
                row[i2 * 4 + j] = f2bf(sv);
                row[12 + i2 * 4 + j] = f2bf(cv);
            }
            row[24 + i2] = f2bf(dvv);
        } else {
            int p = tid - 192;
            ushort16* row = &sX[p * FSTRX + 64];
#pragma unroll
            for (int j = 27; j < 32; ++j) row[j] = 0;
        }
        __syncthreads();
        {
            short8 a0 = *(const short8*)&sX[(wv * 16 + colg) * FSTRX + 64 + quad * 8];
            short8 a1 = *(const short8*)&sY[(wv * 16 + colg) * STRY + quad * 8];
            short8 a2 = *(const short8*)&sY[(wv * 16 + colg) * STRY + 32 + quad * 8];
#pragma unroll
            for (int nt = 0; nt < 2; ++nt) {
                short8 bb0 = *(const short8*)&sWR[(nt * 16 + colg) * STRWR + quad * 8];
                short8 bb1 = *(const short8*)&sWR[(nt * 16 + colg) * STRWR + 32 + quad * 8];
                short8 bb2 = *(const short8*)&sWR[(nt * 16 + colg) * STRWR + 64 + quad * 8];
                f32x4 acc = {0.f, 0.f, 0.f, 0.f};
                acc = __builtin_amdgcn_mfma_f32_16x16x32_bf16(a0, bb0, acc, 0, 0, 0);
                acc = __builtin_amdgcn_mfma_f32_16x16x32_bf16(a1, bb1, acc, 0, 0, 0);
                acc = __builtin_amdgcn_mfma_f32_16x16x32_bf16(a2, bb2, acc, 0, 0, 0);
                float bias = sBR[nt * 16 + colg];
#pragma unroll
                for (int r = 0; r < 4; ++r) {
                    sX[(wv * 16 + quad * 4 + r) * FSTRX + nt * 16 + colg] = f2bf(acc[r] + bias);
                }
            }
        }
        __syncthreads();
        if (tid < 64) {
            int pt = p0 + tid;
            float r0 = 0.f, r1 = 0.f, r2 = 0.f, dd = 0.f;
            const ushort16* hx = &sX[tid * FSTRX];
            const ushort16* hb = &sY[tid * STRY];
#pragma unroll
            for (int k = 0; k < 32; ++k) {
                float hv = bf2f(hx[k]);
                r0 += hv * sWCf[k * 3 + 0];
                r1 += hv * sWCf[k * 3 + 1];
                r2 += hv * sWCf[k * 3 + 2];
            }
#pragma unroll
            for (int k = 0; k < 64; ++k) dd += bf2f(hb[k]) * sWDf[k];
            r0 += sWCf[96]; r1 += sWCf[97]; r2 += sWCf[98]; dd += sWCf[99];
            r0 = 1.f / (1.f + expf(-r0));
            r1 = 1.f / (1.f + expf(-r1));
            r2 = 1.f / (1.f + expf(-r2));
            float sp = (dd > 0.f) ? (dd + log1pf(expf(-dd))) : log1pf(expf(dd));
            if (f32) {
                float4 o4; o4.x = r0; o4.y = r1; o4.z = r2; o4.w = sp;
                ((float4*)out)[pt] = o4;
            } else {
                uint2 o;
                o.x = pack2(r0, r1); o.y = pack2(r2, sp);
                ((uint2*)out)[pt] = o;
            }
        }
    }
}

// ---------------------------------------------------------------------------
extern "C" void kernel_launch(void* const* d_in, const int* in_sizes, int n_in,
                              void* d_out, int out_size, void* d_ws, size_t ws_size,
                              hipStream_t stream) {
    (void)in_sizes; (void)n_in; (void)out_size;

    // SCALINGS with identical libm double math to numpy
    Scal16 sc;
    double g = exp((log(1024.0) - log(16.0)) / 15.0);
    for (int l = 0; l < 16; ++l) sc.s[l] = (float)floor(16.0 * pow(g, (double)l));

    // freqs = 2 ** float32(linspace(0,4,4))
    Freq4 fq;
    float lv[4] = {0.f, 4.f / 3.f, 8.f / 3.f, 4.f};
    for (int j = 0; j < 4; ++j) fq.f[j] = (float)pow(2.0, (double)lv[j]);

    const size_t enc_bytes = (size_t)16 * NPTS * 4;   // 32 MiB packed-bf16 enc
    if (ws_size >= enc_bytes) {
        uint32* enc = (uint32*)d_ws;
        // single launch, 2 phases x 8 XCD-pinned levels + x-corner pairing
        k_hash<<<dim3(2 * 8 * NPTS / 256), dim3(256), 0, stream>>>(d_in[0], d_in[2], enc, sc);
        k_mlp<<<dim3(512), dim3(512), 0, stream>>>(
            d_in[0], enc, d_in[1], d_in[3], d_in[4], d_in[5], d_in[6], d_in[7],
            d_in[8], d_in[9], d_in[10], d_in[11], d_in[12], d_in[13], d_in[14],
            d_out, fq);
    } else {
        k_fused<<<dim3(512), dim3(256), 0, stream>>>(
            d_in[0], d_in[1], d_in[2], d_in[3], d_in[4], d_in[5], d_in[6], d_in[7],
            d_in[8], d_in[9], d_in[10], d_in[11], d_in[12], d_in[13], d_in[14],
            d_out, sc, fq);
    }
}

// Round 9
// 372.796 us; speedup vs baseline: 1.0259x; 1.0029x over previous
//
#include <hip/hip_runtime.h>
#include <math.h>

#define NPTS 524288
#define LOG2T 19
#define TSIZE (1u << LOG2T)
#define TMASK (TSIZE - 1u)

typedef unsigned int uint32;
typedef unsigned short ushort16;

typedef __attribute__((ext_vector_type(8))) short short8;
typedef __attribute__((ext_vector_type(4))) float f32x4;

__device__ __forceinline__ float bf2f(ushort16 u) {
    union { uint32 i; float f; } v; v.i = ((uint32)u) << 16; return v.f;
}
__device__ __forceinline__ ushort16 f2bf(float f) {
    union { float f; uint32 i; } v; v.f = f;
    uint32 r = v.i + 0x7fffu + ((v.i >> 16) & 1u);   // RNE
    return (ushort16)(r >> 16);
}
__device__ __forceinline__ uint32 pack2(float a, float b) {
    return (uint32)f2bf(a) | ((uint32)f2bf(b) << 16);
}
// dtype-flexible scalar load: fp32 or bf16 per runtime flag (block-uniform)
__device__ __forceinline__ float ldin(const void* p, int i, bool f32) {
    return f32 ? ((const float*)p)[i] : bf2f(((const ushort16*)p)[i]);
}

struct Scal16 { float s[16]; };
struct Freq4  { float f[4]; };

// ---------------------------------------------------------------------------
// Kernel A (unchanged, ~206 us measured): level-major hash encode, single
// launch, 2 phases x 8 levels; lvl pinned to one XCD's L2; x-corner pairing
// (~6 L2 requests per (pt,lvl) — ~82% of the L2-request-channel model).
// enc[lvl*NPTS+pt] = packed bf16 (feat0 | feat1<<16)
// ---------------------------------------------------------------------------
__global__ __launch_bounds__(256) void k_hash(const void* __restrict__ pos,
                                              const void* __restrict__ tbl,
                                              uint32* __restrict__ enc,
                                              Scal16 sc) {
    __shared__ int sFlag;
    int tid = threadIdx.x;
    if (tid < 64) {   // dtype detect: positions in [0,1); bf16-misread of fp32 -> garbage
        const ushort16* ph = (const ushort16*)pos;
        float v0 = bf2f(ph[tid]), v1 = bf2f(ph[tid + 64]);
        bool odd = !(fabsf(v0) <= 4.f) || !(fabsf(v1) <= 4.f);
        unsigned long long m = __ballot(odd);
        if (tid == 0) sFlag = (m != 0ull) ? 1 : 0;
    }
    __syncthreads();
    const bool f32 = (sFlag != 0);

    int lvl = ((blockIdx.x >> 14) << 3) + (blockIdx.x & 7);
    int pt = ((blockIdx.x >> 3) & 2047) * 256 + tid;

    float s = sc.s[lvl];
    float x = ldin(pos, 3 * pt, f32), y = ldin(pos, 3 * pt + 1, f32), z = ldin(pos, 3 * pt + 2, f32);
    float sx = x * s, sy = y * s, sz = z * s;
    float fx = floorf(sx), fy = floorf(sy), fz = floorf(sz);
    float cx = ceilf(sx), cy = ceilf(sy), cz = ceilf(sz);   // ceil, NOT floor+1 (matches ref)
    float ox = sx - fx, oy = sy - fy, oz = sz - fz;
    uint32 hx0 = (uint32)(int)fx;                       // prime[0] = 1
    uint32 hx1 = (uint32)(int)cx;
    uint32 hy0 = (uint32)(int)fy * 2654435761u;
    uint32 hy1 = (uint32)(int)cy * 2654435761u;
    uint32 hz0 = (uint32)(int)fz * 805459861u;
    uint32 hz1 = (uint32)(int)cz * 805459861u;
    uint32 base = (uint32)lvl << LOG2T;
    float wx0 = 1.f - ox, wy0 = 1.f - oy, wz0 = 1.f - oz;

    float a0 = 0.f, a1 = 0.f;
    if (f32) {
        const float* tf = (const float*)tbl;
#pragma unroll
        for (int yz = 0; yz < 4; ++yz) {
            uint32 m = ((yz & 1) ? hy1 : hy0) ^ ((yz & 2) ? hz1 : hz0);
            float wyz = ((yz & 1) ? oy : wy0) * ((yz & 2) ? oz : wz0);
            uint32 i0 = ((hx0 ^ m) & TMASK) + base;
            uint32 i1 = ((hx1 ^ m) & TMASK) + base;
            float4 pv = *(const float4*)(tf + (size_t)(i0 & ~1u) * 2);   // 16B pair
            bool lo = !(i0 & 1u);
            float f0 = lo ? pv.x : pv.z, f1 = lo ? pv.y : pv.w;
            float c0, c1;
            if (i1 == (i0 ^ 1u)) { c0 = lo ? pv.z : pv.x; c1 = lo ? pv.w : pv.y; }
            else { float2 tv = ((const float2*)tbl)[i1]; c0 = tv.x; c1 = tv.y; }
            a0 += wyz * (wx0 * f0 + ox * c0);
            a1 += wyz * (wx0 * f1 + ox * c1);
        }
    } else {
#pragma unroll
        for (int cr = 0; cr < 8; ++cr) {
            uint32 h = ((cr & 1) ? hx1 : hx0) ^ ((cr & 2) ? hy1 : hy0) ^ ((cr & 4) ? hz1 : hz0);
            uint32 idx = (h & TMASK) + base;
            uint32 dv = ((const uint32*)tbl)[idx];
            float w = ((cr & 1) ? ox : wx0) * ((cr & 2) ? oy : wy0) * ((cr & 4) ? oz : wz0);
            a0 += w * bf2f((ushort16)(dv & 0xffffu));
            a1 += w * bf2f((ushort16)(dv >> 16));
        }
    }
    enc[(size_t)lvl * NPTS + pt] = pack2(a0, a1);
}

// ---------------------------------------------------------------------------
// Kernel B: R8 structure (2 barriers, 128 pts/iter, 8 waves, wave-private
// rows) with the R6-proven OPERAND-SWAPPED layers: mfma(a=W[n][k], b=X[m][k])
// -> lane (colg,quad) holds features nt*16+quad*4+{0..3} of point colg ->
// ONE uint2 writeback per nt (was 4 scalar u16 + f2bf each). Dir encode uses
// HW __sinf/__cosf with packed uint2 stores; enc staged via uint2 loads.
// Buffers: sX[128][100]: enc(0..31)->h1(0..63), dirs(64..95), rgb_h(0..31)
//          sY[128][72] : h0(0..63)->base(0..63)
// ---------------------------------------------------------------------------
#define STRY 72
#define STRW0 40
#define STRW12 72
#define STRWR 104
#define MSTRX 100
#define PPI 128                 // points per iteration
#define NIT (NPTS / PPI)

__global__ __launch_bounds__(512) void k_mlp(
    const void* __restrict__ pos,   // for dtype detection only
    const uint32* __restrict__ enc, const void* __restrict__ dirs,
    const void* __restrict__ w0, const void* __restrict__ b0,
    const void* __restrict__ w1, const void* __restrict__ b1,
    const void* __restrict__ w2, const void* __restrict__ b2,
    const void* __restrict__ wr, const void* __restrict__ br,
    const void* __restrict__ wc, const void* __restrict__ bc,
    const void* __restrict__ wd, const void* __restrict__ bd,
    void* __restrict__ out, Freq4 fq)
{
    __shared__ __align__(16) ushort16 sX[PPI * MSTRX];
    __shared__ __align__(16) ushort16 sY[PPI * STRY];
    __shared__ __align__(16) ushort16 sW0[64 * STRW0];
    __shared__ __align__(16) ushort16 sW1[64 * STRW12];
    __shared__ __align__(16) ushort16 sW2[64 * STRW12];
    __shared__ __align__(16) ushort16 sWR[32 * STRWR];
    __shared__ __align__(16) ushort16 sW4[16 * STRWR];
    __shared__ __align__(16) float sB0[64], sB1[64], sB2[64], sBR[32], sFB[4];
    __shared__ int sFlag;

    int tid = threadIdx.x;

    if (tid < 64) {
        const ushort16* ph = (const ushort16*)pos;
        float v0 = bf2f(ph[tid]), v1 = bf2f(ph[tid + 64]);
        bool odd = !(fabsf(v0) <= 4.f) || !(fabsf(v1) <= 4.f);
        unsigned long long m = __ballot(odd);
        if (tid == 0) sFlag = (m != 0ull) ? 1 : 0;
    }
    __syncthreads();
    const bool f32 = (sFlag != 0);

    // ---- stage weights once (transpose to [n][k], bf16) ----
    for (int i = tid; i < 2048; i += 512) { int k = i >> 6, n = i & 63; sW0[n * STRW0 + k] = f2bf(ldin(w0, i, f32)); }
    for (int i = tid; i < 4096; i += 512) { int k = i >> 6, n = i & 63; sW1[n * STRW12 + k] = f2bf(ldin(w1, i, f32)); }
    for (int i = tid; i < 4096; i += 512) { int k = i >> 6, n = i & 63; sW2[n * STRW12 + k] = f2bf(ldin(w2, i, f32)); }
    // wr[91][32]: rows 0..26 (dir) -> k=r; rows 27..90 (base) -> k=r+5
    for (int i = tid; i < 2912; i += 512) {
        int r = i >> 5, n = i & 31; int k = (r < 27) ? r : r + 5;
        sWR[n * STRWR + k] = f2bf(ldin(wr, i, f32));
    }
    if (tid < 160) { int n = tid / 5, k = 27 + tid % 5; sWR[n * STRWR + k] = 0; }  // zero pad k=27..31
    // W4[16][96]: k 0..63 = base, k 64..95 = rgb_h; rows 0..2 = wc, row 3 = wd
    for (int i = tid; i < 1536; i += 512) {
        int n = i / 96, j = i % 96;
        float v = 0.f;
        if (n == 3 && j < 64) v = ldin(wd, j, f32);
        else if (n < 3 && j >= 64) v = ldin(wc, (j - 64) * 3 + n, f32);
        sW4[n * STRWR + j] = f2bf(v);
    }
    if (tid < 64) { sB0[tid] = ldin(b0, tid, f32); sB1[tid] = ldin(b1, tid, f32); sB2[tid] = ldin(b2, tid, f32); }
    if (tid < 32) sBR[tid] = ldin(br, tid, f32);
    if (tid < 3) sFB[tid] = ldin(bc, tid, f32);
    if (tid == 3) sFB[3] = ldin(bd, 0, f32);

    int lane = tid & 63, wv = tid >> 6;          // wv in [0,8)
    int colg = lane & 15, quad = lane >> 4;
    int myrow = wv * 16 + colg;                  // this lane's point row in [0,128)

    for (int c = blockIdx.x; c < NIT; c += gridDim.x) {
        int p0 = c * PPI;
        __syncthreads();   // B1: prev iteration finale reads done (covers weight staging on iter 0)

        // ---- stage enc -> sX cols 0..31 (uint2 loads, 2 pts per job) ----
        for (int i = tid; i < 1024; i += 512) {
            int l = i >> 6, p2 = (i & 63) * 2;
            uint2 e = *(const uint2*)&enc[(size_t)l * NPTS + p0 + p2];
            *(uint32*)&sX[p2 * MSTRX + 2 * l] = e.x;
            *(uint32*)&sX[(p2 + 1) * MSTRX + 2 * l] = e.y;
        }
        // ---- NeRF dir encode -> sX cols 64..95 (HW sin/cos, packed stores) ----
        if (tid < 384) {
            int p = tid / 3, i2 = tid - 3 * (tid / 3);
            float dvv = ldin(dirs, 3 * (p0 + p) + i2, f32);
            ushort16* row = &sX[p * MSTRX + 64];
            float td = 6.28318530717958647692f * dvv;
            float a0 = td * fq.f[0], a1 = td * fq.f[1], a2 = td * fq.f[2], a3 = td * fq.f[3];
            uint2 sv, cv;
            sv.x = pack2(__sinf(a0), __sinf(a1));
            sv.y = pack2(__sinf(a2), __sinf(a3));
            cv.x = pack2(__cosf(a0), __cosf(a1));
            cv.y = pack2(__cosf(a2), __cosf(a3));
            *(uint2*)&row[i2 * 4] = sv;          // byte off 128+8*i2 within row: 8B aligned
            *(uint2*)&row[12 + i2 * 4] = cv;     // byte off 152+8*i2: 8B aligned
            row[24 + i2] = f2bf(dvv);
        } else {
            int p = tid - 384;   // 128 threads zero cols 91..95
            ushort16* row = &sX[p * MSTRX + 64];
#pragma unroll
            for (int j = 27; j < 32; ++j) row[j] = 0;
        }
        __syncthreads();   // B2: enc + dir staged

        // ---- L0: relu(enc @ w0 + b0) -> sY[0..63] (operand-swapped, packed WB) ----
        {
            short8 xb = *(const short8*)&sX[myrow * MSTRX + quad * 8];
#pragma unroll
            for (int nt = 0; nt < 4; ++nt) {
                short8 a = *(const short8*)&sW0[(nt * 16 + colg) * STRW0 + quad * 8];
                f32x4 acc = {0.f, 0.f, 0.f, 0.f};
                acc = __builtin_amdgcn_mfma_f32_16x16x32_bf16(a, xb, acc, 0, 0, 0);
                float4 bi = *(const float4*)&sB0[nt * 16 + quad * 4];
                uint2 o;
                o.x = pack2(fmaxf(acc[0] + bi.x, 0.f), fmaxf(acc[1] + bi.y, 0.f));
                o.y = pack2(fmaxf(acc[2] + bi.z, 0.f), fmaxf(acc[3] + bi.w, 0.f));
                *(uint2*)&sY[myrow * STRY + nt * 16 + quad * 4] = o;
            }
        }
        // ---- L1: relu(h0 @ w1 + b1) -> sX[0..63] ----
        {
            short8 xb0 = *(const short8*)&sY[myrow * STRY + quad * 8];
            short8 xb1 = *(const short8*)&sY[myrow * STRY + 32 + quad * 8];
#pragma unroll
            for (int nt = 0; nt < 4; ++nt) {
                short8 a0 = *(const short8*)&sW1[(nt * 16 + colg) * STRW12 + quad * 8];
                short8 a1 = *(const short8*)&sW1[(nt * 16 + colg) * STRW12 + 32 + quad * 8];
                f32x4 acc = {0.f, 0.f, 0.f, 0.f};
                acc = __builtin_amdgcn_mfma_f32_16x16x32_bf16(a0, xb0, acc, 0, 0, 0);
                acc = __builtin_amdgcn_mfma_f32_16x16x32_bf16(a1, xb1, acc, 0, 0, 0);
                float4 bi = *(const float4*)&sB1[nt * 16 + quad * 4];
                uint2 o;
                o.x = pack2(fmaxf(acc[0] + bi.x, 0.f), fmaxf(acc[1] + bi.y, 0.f));
                o.y = pack2(fmaxf(acc[2] + bi.z, 0.f), fmaxf(acc[3] + bi.w, 0.f));
                *(uint2*)&sX[myrow * MSTRX + nt * 16 + quad * 4] = o;
            }
        }
        // ---- L2: base = h1 @ w2 + b2 -> sY[0..63] (linear) ----
        {
            short8 xb0 = *(const short8*)&sX[myrow * MSTRX + quad * 8];
            short8 xb1 = *(const short8*)&sX[myrow * MSTRX + 32 + quad * 8];
#pragma unroll
            for (int nt = 0; nt < 4; ++nt) {
                short8 a0 = *(const short8*)&sW2[(nt * 16 + colg) * STRW12 + quad * 8];
                short8 a1 = *(const short8*)&sW2[(nt * 16 + colg) * STRW12 + 32 + quad * 8];
                f32x4 acc = {0.f, 0.f, 0.f, 0.f};
                acc = __builtin_amdgcn_mfma_f32_16x16x32_bf16(a0, xb0, acc, 0, 0, 0);
                acc = __builtin_amdgcn_mfma_f32_16x16x32_bf16(a1, xb1, acc, 0, 0, 0);
                float4 bi = *(const float4*)&sB2[nt * 16 + quad * 4];
                uint2 o;
                o.x = pack2(acc[0] + bi.x, acc[1] + bi.y);
                o.y = pack2(acc[2] + bi.z, acc[3] + bi.w);
                *(uint2*)&sY[myrow * STRY + nt * 16 + quad * 4] = o;
            }
        }
        // ---- Lr: rgb_h = [dir|base] @ wr + br -> sX[0..31] (K=96; overwrites h1 after L2 read) ----
        {
            short8 xb0 = *(const short8*)&sX[myrow * MSTRX + 64 + quad * 8];
            short8 xb1 = *(const short8*)&sY[myrow * STRY + quad * 8];
            short8 xb2 = *(const short8*)&sY[myrow * STRY + 32 + quad * 8];
#pragma unroll
            for (int nt = 0; nt < 2; ++nt) {
                short8 a0 = *(const short8*)&sWR[(nt * 16 + colg) * STRWR + quad * 8];
                short8 a1 = *(const short8*)&sWR[(nt * 16 + colg) * STRWR + 32 + quad * 8];
                short8 a2 = *(const short8*)&sWR[(nt * 16 + colg) * STRWR + 64 + quad * 8];
                f32x4 acc = {0.f, 0.f, 0.f, 0.f};
                acc = __builtin_amdgcn_mfma_f32_16x16x32_bf16(a0, xb0, acc, 0, 0, 0);
                acc = __builtin_amdgcn_mfma_f32_16x16x32_bf16(a1, xb1, acc, 0, 0, 0);
                acc = __builtin_amdgcn_mfma_f32_16x16x32_bf16(a2, xb2, acc, 0, 0, 0);
                float4 bi = *(const float4*)&sBR[nt * 16 + quad * 4];
                uint2 o;
                o.x = pack2(acc[0] + bi.x, acc[1] + bi.y);
                o.y = pack2(acc[2] + bi.z, acc[3] + bi.w);
                *(uint2*)&sX[myrow * MSTRX + nt * 16 + quad * 4] = o;
            }
        }
        // ---- finale: D' = W4 @ [base|rgb_h]^T; quad0 lane holds (r,g,b,dd) ----
        {
            short8 xb0 = *(const short8*)&sY[myrow * STRY + quad * 8];        // base 0..31
            short8 xb1 = *(const short8*)&sY[myrow * STRY + 32 + quad * 8];   // base 32..63
            short8 xb2 = *(const short8*)&sX[myrow * MSTRX + quad * 8];       // rgb_h 0..31
            short8 a0 = *(const short8*)&sW4[colg * STRWR + quad * 8];
            short8 a1 = *(const short8*)&sW4[colg * STRWR + 32 + quad * 8];
            short8 a2 = *(const short8*)&sW4[colg * STRWR + 64 + quad * 8];
            f32x4 acc = {0.f, 0.f, 0.f, 0.f};
            acc = __builtin_amdgcn_mfma_f32_16x16x32_bf16(a0, xb0, acc, 0, 0, 0);
            acc = __builtin_amdgcn_mfma_f32_16x16x32_bf16(a1, xb1, acc, 0, 0, 0);
            acc = __builtin_amdgcn_mfma_f32_16x16x32_bf16(a2, xb2, acc, 0, 0, 0);
            if (quad == 0) {
                float r0 = acc[0] + sFB[0], r1 = acc[1] + sFB[1], r2 = acc[2] + sFB[2], dd = acc[3] + sFB[3];
                r0 = 1.f / (1.f + expf(-r0));
                r1 = 1.f / (1.f + expf(-r1));
                r2 = 1.f / (1.f + expf(-r2));
                float sp = (dd > 0.f) ? (dd + log1pf(expf(-dd))) : log1pf(expf(dd));
                int pt = p0 + myrow;
                if (f32) {
                    float4 o4; o4.x = r0; o4.y = r1; o4.z = r2; o4.w = sp;
                    ((float4*)out)[pt] = o4;
                } else {
                    uint2 o; o.x = pack2(r0, r1); o.y = pack2(r2, sp);
                    ((uint2*)out)[pt] = o;
                }
            }
        }
        // no B3: finale reads only own-wave rows; B1 protects next staging
    }
}

// ---------------------------------------------------------------------------
// Fallback: the round-3 PASSING fully fused kernel (used if ws too small).
// ---------------------------------------------------------------------------
#define FSTRX 104
__global__ __launch_bounds__(256) void k_fused(
    const void* __restrict__ pos, const void* __restrict__ dirs,
    const void* __restrict__ tbl,
    const void* __restrict__ w0, const void* __restrict__ b0,
    const void* __restrict__ w1, const void* __restrict__ b1,
    const void* __restrict__ w2, const void* __restrict__ b2,
    const void* __restrict__ wr, const void* __restrict__ br,
    const void* __restrict__ wc, const void* __restrict__ bc,
    const void* __restrict__ wd, const void* __restrict__ bd,
    void* __restrict__ out, Scal16 sc, Freq4 fq)
{
    __shared__ __align__(16) ushort16 sX[64 * FSTRX];
    __shared__ __align__(16) ushort16 sY[64 * STRY];
    __shared__ __align__(16) ushort16 sW0[64 * STRW0];
    __shared__ __align__(16) ushort16 sW1[64 * STRW12];
    __shared__ __align__(16) ushort16 sW2[64 * STRW12];
    __shared__ __align__(16) ushort16 sWR[32 * STRWR];
    __shared__ float sB0[64], sB1[64], sB2[64], sBR[32];
    __shared__ float sWCf[100];
    __shared__ float sWDf[64];
    __shared__ float sPosF[192];
    __shared__ int sFlag;

    int tid = threadIdx.x;
    if (tid < 64) {
        const ushort16* ph = (const ushort16*)pos;
        float v0 = bf2f(ph[tid]), v1 = bf2f(ph[tid + 64]);
        bool odd = !(fabsf(v0) <= 4.f) || !(fabsf(v1) <= 4.f);
        unsigned long long m = __ballot(odd);
        if (tid == 0) sFlag = (m != 0ull) ? 1 : 0;
    }
    __syncthreads();
    const bool f32 = (sFlag != 0);

    for (int i = tid; i < 2048; i += 256) { int k = i >> 6, n = i & 63; sW0[n * STRW0 + k] = f2bf(ldin(w0, i, f32)); }
    for (int i = tid; i < 4096; i += 256) { int k = i >> 6, n = i & 63; sW1[n * STRW12 + k] = f2bf(ldin(w1, i, f32)); }
    for (int i = tid; i < 4096; i += 256) { int k = i >> 6, n = i & 63; sW2[n * STRW12 + k] = f2bf(ldin(w2, i, f32)); }
    for (int i = tid; i < 2912; i += 256) {
        int r = i >> 5, n = i & 31; int k = (r < 27) ? r : r + 5;
        sWR[n * STRWR + k] = f2bf(ldin(wr, i, f32));
    }
    if (tid < 160) { int n = tid / 5, k = 27 + tid % 5; sWR[n * STRWR + k] = 0; }
    if (tid < 64) { sB0[tid] = ldin(b0, tid, f32); sB1[tid] = ldin(b1, tid, f32);
                    sB2[tid] = ldin(b2, tid, f32); sWDf[tid] = ldin(wd, tid, f32); }
    if (tid < 32) sBR[tid] = ldin(br, tid, f32);
    if (tid < 96) sWCf[tid] = ldin(wc, tid, f32);
    if (tid == 96) { sWCf[96] = ldin(bc, 0, f32); sWCf[97] = ldin(bc, 1, f32);
                     sWCf[98] = ldin(bc, 2, f32); sWCf[99] = ldin(bd, 0, f32); }

    int lane = tid & 63, wv = tid >> 6;
    int colg = lane & 15, quad = lane >> 4;
    int myl = tid & 15;
    float mys = sc.s[myl];
    uint32 mybase = (uint32)myl << LOG2T;

    for (int c = blockIdx.x; c < NPTS / 64; c += gridDim.x) {
        int p0 = c * 64;
        __syncthreads();
        if (tid < 192) sPosF[tid] = ldin(pos, p0 * 3 + tid, f32);
        __syncthreads();
#pragma unroll
        for (int ii = 0; ii < 4; ++ii) {
            int p = (tid >> 4) + 16 * ii;
            float x = sPosF[3 * p], y = sPosF[3 * p + 1], z = sPosF[3 * p + 2];
            float sx = x * mys, sy = y * mys, sz = z * mys;
            float fx = floorf(sx), fy = floorf(sy), fz = floorf(sz);
            float cx = ceilf(sx), cy = ceilf(sy), cz = ceilf(sz);
            float ox = sx - fx, oy = sy - fy, oz = sz - fz;
            uint32 hx0 = (uint32)(int)fx;
            uint32 hx1 = (uint32)(int)cx;
            uint32 hy0 = (uint32)(int)fy * 2654435761u;
            uint32 hy1 = (uint32)(int)cy * 2654435761u;
            uint32 hz0 = (uint32)(int)fz * 805459861u;
            uint32 hz1 = (uint32)(int)cz * 805459861u;
            float wx0 = 1.f - ox, wy0 = 1.f - oy, wz0 = 1.f - oz;
            float a0 = 0.f, a1 = 0.f;
#pragma unroll
            for (int cr = 0; cr < 8; ++cr) {
                uint32 h = ((cr & 1) ? hx1 : hx0) ^ ((cr & 2) ? hy1 : hy0) ^ ((cr & 4) ? hz1 : hz0);
                uint32 idx = (h & TMASK) + mybase;
                float t0, t1;
                if (f32) { float2 tv = ((const float2*)tbl)[idx]; t0 = tv.x; t1 = tv.y; }
                else { uint32 dv = ((const uint32*)tbl)[idx]; t0 = bf2f((ushort16)(dv & 0xffffu)); t1 = bf2f((ushort16)(dv >> 16)); }
                float w = ((cr & 1) ? ox : wx0) * ((cr & 2) ? oy : wy0) * ((cr & 4) ? oz : wz0);
                a0 += w * t0; a1 += w * t1;
            }
            *(uint32*)&sX[p * FSTRX + 2 * myl] = pack2(a0, a1);
        }
        __syncthreads();
        {
            short8 a = *(const short8*)&sX[(wv * 16 + colg) * FSTRX + quad * 8];
#pragma unroll
            for (int nt = 0; nt < 4; ++nt) {
                short8 bb = *(const short8*)&sW0[(nt * 16 + colg) * STRW0 + quad * 8];
                f32x4 acc = {0.f, 0.f, 0.f, 0.f};
                acc = __builtin_amdgcn_mfma_f32_16x16x32_bf16(a, bb, acc, 0, 0, 0);
                float bias = sB0[nt * 16 + colg];
#pragma unroll
                for (int r = 0; r < 4; ++r) {
                    float v = fmaxf(acc[r] + bias, 0.f);
                    sY[(wv * 16 + quad * 4 + r) * STRY + nt * 16 + colg] = f2bf(v);
                }
            }
        }
        __syncthreads();
        {
            short8 a0 = *(const short8*)&sY[(wv * 16 + colg) * STRY + quad * 8];
            short8 a1 = *(const short8*)&sY[(wv * 16 + colg) * STRY + 32 + quad * 8];
#pragma unroll
            for (int nt = 0; nt < 4; ++nt) {
                short8 bb0 = *(const short8*)&sW1[(nt * 16 + colg) * STRW12 + quad * 8];
                short8 bb1 = *(const short8*)&sW1[(nt * 16 + colg) * STRW12 + 32 + quad * 8];
                f32x4 acc = {0.f, 0.f, 0.f, 0.f};
                acc = __builtin_amdgcn_mfma_f32_16x16x32_bf16(a0, bb0, acc, 0, 0, 0);
                acc = __builtin_amdgcn_mfma_f32_16x16x32_bf16(a1, bb1, acc, 0, 0, 0);
                float bias = sB1[nt * 16 + colg];
#pragma unroll
                for (int r = 0; r < 4; ++r) {
                    float v = fmaxf(acc[r] + bias, 0.f);
                    sX[(wv * 16 + quad * 4 + r) * FSTRX + nt * 16 + colg] = f2bf(v);
                }
            }
        }
        __syncthreads();
        {
            short8 a0 = *(const short8*)&sX[(wv * 16 + colg) * FSTRX + quad * 8];
            short8 a1 = *(const short8*)&sX[(wv * 16 + colg) * FSTRX + 32 + quad * 8];
#pragma unroll
            for (int nt = 0; nt < 4; ++nt) {
                short8 bb0 = *(const short8*)&sW2[(nt * 16 + colg) * STRW12 + quad * 8];
                short8 bb1 = *(const short8*)&sW2[(nt * 16 + colg) * STRW12 + 32 + quad * 8];
                f32x4 acc = {0.f, 0.f, 0.f, 0.f};
                acc = __builtin_amdgcn_mfma_f32_16x16x32_bf16(a0, bb0, acc, 0, 0, 0);
                acc = __builtin_amdgcn_mfma_f32_16x16x32_bf16(a1, bb1, acc, 0, 0, 0);
                float bias = sB2[nt * 16 + colg];
#pragma unroll
                for (int r = 0; r < 4; ++r) {
                    sY[(wv * 16 + quad * 4 + r) * STRY + nt * 16 + colg] = f2bf(acc[r] + bias);
                }
            }
        }
        if (tid < 192) {
            int p = tid / 3, i2 = tid % 3;
            float dvv = ldin(dirs, 3 * (p0 + p) + i2, f32);
            ushort16* row = &sX[p * FSTRX + 64];
            float td = 6.28318530717958647692f * dvv;
#pragma unroll
            for (int j = 0; j < 4; ++j) {
                float arg = td * fq.f[j];
                float sv, cv;
                sincosf(arg, &sv, &cv);
                row[i2 * 4 + j] = f2bf(sv);
                row[12 + i2 * 4 + j] = f2bf(cv);
            }
            row[24 + i2] = f2bf(dvv);
        } else {
            int p = tid - 192;
            ushort16* row = &sX[p * FSTRX + 64];
#pragma unroll
            for (int j = 27; j < 32; ++j) row[j] = 0;
        }
        __syncthreads();
        {
            short8 a0 = *(const short8*)&sX[(wv * 16 + colg) * FSTRX + 64 + quad * 8];
            short8 a1 = *(const short8*)&sY[(wv * 16 + colg) * STRY + quad * 8];
            short8 a2 = *(const short8*)&sY[(wv * 16 + colg) * STRY + 32 + quad * 8];
#pragma unroll
            for (int nt = 0; nt < 2; ++nt) {
                short8 bb0 = *(const short8*)&sWR[(nt * 16 + colg) * STRWR + quad * 8];
                short8 bb1 = *(const short8*)&sWR[(nt * 16 + colg) * STRWR + 32 + quad * 8];
                short8 bb2 = *(const short8*)&sWR[(nt * 16 + colg) * STRWR + 64 + quad * 8];
                f32x4 acc = {0.f, 0.f, 0.f, 0.f};
                acc = __builtin_amdgcn_mfma_f32_16x16x32_bf16(a0, bb0, acc, 0, 0, 0);
                acc = __builtin_amdgcn_mfma_f32_16x16x32_bf16(a1, bb1, acc, 0, 0, 0);
                acc = __builtin_amdgcn_mfma_f32_16x16x32_bf16(a2, bb2, acc, 0, 0, 0);
                float bias = sBR[nt * 16 + colg];
#pragma unroll
                for (int r = 0; r < 4; ++r) {
                    sX[(wv * 16 + quad * 4 + r) * FSTRX + nt * 16 + colg] = f2bf(acc[r] + bias);
                }
            }
        }
        __syncthreads();
        if (tid < 64) {
            int pt = p0 + tid;
            float r0 = 0.f, r1 = 0.f, r2 = 0.f, dd = 0.f;
            const ushort16* hx = &sX[tid * FSTRX];
            const ushort16* hb = &sY[tid * STRY];
#pragma unroll
            for (int k = 0; k < 32; ++k) {
                float hv = bf2f(hx[k]);
                r0 += hv * sWCf[k * 3 + 0];
                r1 += hv * sWCf[k * 3 + 1];
                r2 += hv * sWCf[k * 3 + 2];
            }
#pragma unroll
            for (int k = 0; k < 64; ++k) dd += bf2f(hb[k]) * sWDf[k];
            r0 += sWCf[96]; r1 += sWCf[97]; r2 += sWCf[98]; dd += sWCf[99];
            r0 = 1.f / (1.f + expf(-r0));
            r1 = 1.f / (1.f + expf(-r1));
            r2 = 1.f / (1.f + expf(-r2));
            float sp = (dd > 0.f) ? (dd + log1pf(expf(-dd))) : log1pf(expf(dd));
            if (f32) {
                float4 o4; o4.x = r0; o4.y = r1; o4.z = r2; o4.w = sp;
                ((float4*)out)[pt] = o4;
            } else {
                uint2 o;
                o.x = pack2(r0, r1); o.y = pack2(r2, sp);
                ((uint2*)out)[pt] = o;
            }
        }
    }
}

// ---------------------------------------------------------------------------
extern "C" void kernel_launch(void* const* d_in, const int* in_sizes, int n_in,
                              void* d_out, int out_size, void* d_ws, size_t ws_size,
                              hipStream_t stream) {
    (void)in_sizes; (void)n_in; (void)out_size;

    // SCALINGS with identical libm double math to numpy
    Scal16 sc;
    double g = exp((log(1024.0) - log(16.0)) / 15.0);
    for (int l = 0; l < 16; ++l) sc.s[l] = (float)floor(16.0 * pow(g, (double)l));

    // freqs = 2 ** float32(linspace(0,4,4))
    Freq4 fq;
    float lv[4] = {0.f, 4.f / 3.f, 8.f / 3.f, 4.f};
    for (int j = 0; j < 4; ++j) fq.f[j] = (float)pow(2.0, (double)lv[j]);

    const size_t enc_bytes = (size_t)16 * NPTS * 4;   // 32 MiB packed-bf16 enc
    if (ws_size >= enc_bytes) {
        uint32* enc = (uint32*)d_ws;
        // single launch, 2 phases x 8 XCD-pinned levels + x-corner pairing
        k_hash<<<dim3(2 * 8 * NPTS / 256), dim3(256), 0, stream>>>(d_in[0], d_in[2], enc, sc);
        k_mlp<<<dim3(512), dim3(512), 0, stream>>>(
            d_in[0], enc, d_in[1], d_in[3], d_in[4], d_in[5], d_in[6], d_in[7],
            d_in[8], d_in[9], d_in[10], d_in[11], d_in[12], d_in[13], d_in[14],
            d_out, fq);
    } else {
        k_fused<<<dim3(512), dim3(256), 0, stream>>>(
            d_in[0], d_in[1], d_in[2], d_in[3], d_in[4], d_in[5], d_in[6], d_in[7],
            d_in[8], d_in[9], d_in[10], d_in[11], d_in[12], d_in[13], d_in[14],
            d_out, sc, fq);
    }
}